// Round 1
// baseline (4519.922 us; speedup 1.0000x reference)
//
#include <hip/hip_runtime.h>
#include <hip/hip_bf16.h>
#include <math.h>

#define BB 512
#define SS 512
#define MM 64
#define DK 128
#define DV 256
#define DF 128
#define CHUNK 16
#define NCHUNK (SS/CHUNK)

// workspace layout (float offsets)
#define WS_ACC 0                      // [0]=loss_sum, [1]=mask_cnt
#define WS_ET  16                     // eraseT [DV][DV]  (eT[j*DV+d] = erase_w[d][j])
#define WS_AT  (WS_ET + DV*DV)        // addT   [DV][DV]
#define WS_KT  (WS_AT + DV*DV)        // keyT   [DK][MM]  (kT[k*MM+m] = key_mem[m][k])
#define WS_IT  (WS_KT + DK*MM)        // inputT [DK][DF]
#define WS_RT  (WS_IT + DK*DF)        // readT  [DV+DF][DF]
#define WS_TOTAL (WS_RT + (DV+DF)*DF)

__global__ void prep_kernel(const float* __restrict__ ew, const float* __restrict__ aw,
                            const float* __restrict__ km, const float* __restrict__ iw,
                            const float* __restrict__ rw, float* __restrict__ ws) {
    int tid = blockIdx.x * 256 + threadIdx.x;
    int stride = gridDim.x * 256;
    if (tid < 2) ws[WS_ACC + tid] = 0.0f;
    for (int i = tid; i < DV*DV; i += stride) {
        int j = i / DV, d = i % DV;
        ws[WS_ET + i] = ew[d*DV + j];
        ws[WS_AT + i] = aw[d*DV + j];
    }
    for (int i = tid; i < DK*MM; i += stride) {
        int k = i / MM, m = i % MM;
        ws[WS_KT + i] = km[m*DK + k];
    }
    for (int i = tid; i < DK*DF; i += stride) {
        int k = i / DF, f = i % DF;
        ws[WS_IT + i] = iw[f*DK + k];
    }
    for (int i = tid; i < (DV+DF)*DF; i += stride) {
        int j = i / DF, f = i % DF;
        ws[WS_RT + i] = rw[f*(DV+DF) + j];
    }
}

__device__ __forceinline__ float sigmoidf_(float x) { return 1.0f / (1.0f + __expf(-x)); }

__launch_bounds__(256, 2)
__global__ void dkvmn_kernel(const int* __restrict__ q_data, const int* __restrict__ qa_data,
                             const float* __restrict__ target,
                             const float* __restrict__ q_embed, const float* __restrict__ qa_embed,
                             const float* __restrict__ init_mv,
                             const float* __restrict__ erase_b, const float* __restrict__ add_b,
                             const float* __restrict__ input_b, const float* __restrict__ read_b,
                             const float* __restrict__ predict_w, const float* __restrict__ predict_b,
                             float* __restrict__ ws, float* __restrict__ out) {
    __shared__ float q_lds[CHUNK][DK];   // 8KB ; reused for rce after ie
    __shared__ float qa_lds[CHUNK][DV];  // 16KB
    __shared__ float w_lds[CHUNK][MM];   // 4KB
    __shared__ float er_lds[CHUNK][DV];  // 16KB ; reused for read after recurrence
    __shared__ float ad_lds[CHUNK][DV];  // 16KB ; [s][0..127] reused for ie

    const int b    = blockIdx.x;
    const int tid  = threadIdx.x;
    const int lane = tid & 63;
    const int wave = tid >> 6;

    const float* eT = ws + WS_ET;
    const float* aT = ws + WS_AT;
    const float* kT = ws + WS_KT;
    const float* iT = ws + WS_IT;
    const float* rT = ws + WS_RT;

    // Mv state in registers: thread owns column d = tid (DV == blockDim)
    float mv[MM];
    #pragma unroll
    for (int m = 0; m < MM; ++m) mv[m] = init_mv[m*DV + tid];

    const float eb = erase_b[tid];
    const float ab = add_b[tid];
    const float pw_lo = predict_w[lane];
    const float pw_hi = predict_w[lane + 64];
    float local_loss = 0.0f, local_cnt = 0.0f;

    for (int c = 0; c < NCHUNK; ++c) {
        const int s0 = c * CHUNK;
        __syncthreads();  // previous chunk's pred phase done with q_lds

        // ---- gather embeddings for the chunk ----
        for (int i = tid; i < CHUNK*DK; i += 256) {
            int r = i >> 7, col = i & 127;
            int idx = q_data[b*SS + s0 + r];
            q_lds[r][col] = q_embed[idx*DK + col];
        }
        for (int i = tid; i < CHUNK*DV; i += 256) {
            int r = i >> 8, col = i & 255;
            int idx = qa_data[b*SS + s0 + r];
            qa_lds[r][col] = qa_embed[idx*DV + col];
        }
        __syncthreads();

        // ---- w = softmax(q @ K^T): one wave per s-row, lane = m ----
        for (int r = wave; r < CHUNK; r += 4) {
            float sc = 0.0f;
            #pragma unroll 8
            for (int k = 0; k < DK; ++k) sc = fmaf(q_lds[r][k], kT[k*MM + lane], sc);
            float mx = sc;
            #pragma unroll
            for (int off = 32; off; off >>= 1) mx = fmaxf(mx, __shfl_xor(mx, off));
            float e = __expf(sc - mx);
            float sum = e;
            #pragma unroll
            for (int off = 32; off; off >>= 1) sum += __shfl_xor(sum, off);
            w_lds[r][lane] = e / sum;
        }

        // ---- erase/add matvecs, register-blocked over the chunk (thread = output d) ----
        {
            float acc_e[CHUNK], acc_a[CHUNK];
            #pragma unroll
            for (int s = 0; s < CHUNK; ++s) { acc_e[s] = eb; acc_a[s] = ab; }
            for (int j = 0; j < DV; ++j) {
                float ewv = eT[j*DV + tid];
                float awv = aT[j*DV + tid];
                #pragma unroll
                for (int s = 0; s < CHUNK; ++s) {
                    float qv = qa_lds[s][j];   // LDS broadcast
                    acc_e[s] = fmaf(qv, ewv, acc_e[s]);
                    acc_a[s] = fmaf(qv, awv, acc_a[s]);
                }
            }
            #pragma unroll
            for (int s = 0; s < CHUNK; ++s) {
                er_lds[s][tid] = sigmoidf_(acc_e[s]);
                ad_lds[s][tid] = tanhf(acc_a[s]);
            }
        }
        __syncthreads();

        // ---- sequential recurrence over the chunk; Mv in registers ----
        for (int s = 0; s < CHUNK; ++s) {
            float e = er_lds[s][tid], a = ad_lds[s][tid];
            float rd = 0.0f;
            #pragma unroll
            for (int m = 0; m < MM; ++m) {
                float wm = w_lds[s][m];            // LDS broadcast
                rd = fmaf(wm, mv[m], rd);          // read uses pre-update Mv
                float t1 = fmaf(-mv[m], e, a);     // a - mv*e
                mv[m] = fmaf(wm, t1, mv[m]);       // mv += w*(a - mv*e)
            }
            er_lds[s][tid] = rd;                   // overwrite erase with read
        }
        __syncthreads();

        // ---- ie = tanh(q @ input_w^T + b) into ad_lds[s][0..127] ----
        #pragma unroll
        for (int rep = 0; rep < (CHUNK*DF)/256; ++rep) {
            int idx = rep*256 + tid;
            int s = idx >> 7, f = idx & 127;
            float acc = input_b[f];
            #pragma unroll 8
            for (int k = 0; k < DK; ++k) acc = fmaf(q_lds[s][k], iT[k*DF + f], acc);
            ad_lds[s][f] = tanhf(acc);
        }
        __syncthreads();

        // ---- rce = tanh(concat(read, ie) @ read_w^T + b) into q_lds ----
        #pragma unroll
        for (int rep = 0; rep < (CHUNK*DF)/256; ++rep) {
            int idx = rep*256 + tid;
            int s = idx >> 7, f = idx & 127;
            float acc = read_b[f];
            #pragma unroll 8
            for (int j = 0; j < DV; ++j) acc = fmaf(er_lds[s][j], rT[j*DF + f], acc);
            #pragma unroll 8
            for (int j = 0; j < DF; ++j) acc = fmaf(ad_lds[s][j], rT[(DV+j)*DF + f], acc);
            q_lds[s][f] = tanhf(acc);
        }
        __syncthreads();

        // ---- pred + outputs + loss: one wave per s-row ----
        for (int r = wave; r < CHUNK; r += 4) {
            float p = pw_lo * q_lds[r][lane] + pw_hi * q_lds[r][lane + 64];
            #pragma unroll
            for (int off = 32; off; off >>= 1) p += __shfl_xor(p, off);
            if (lane == 0) {
                p += predict_b[0];
                int gi = b*SS + s0 + r;
                float t = target[gi];
                bool mask = t >= 0.0f;
                out[gi] = sigmoidf_(p);                              // pred_logit
                float pm = mask ? p : 0.0f;
                out[BB*SS + 1 + gi] = sigmoidf_(pm);                 // filtered_pred
                out[2*BB*SS + 1 + gi] = mask ? t : 0.0f;             // filtered_target
                if (mask) {
                    float bce = fmaxf(p, 0.0f) - p*t + log1pf(__expf(-fabsf(p)));
                    local_loss += bce;
                    local_cnt  += 1.0f;
                }
            }
        }
    }

    // loss partials: wave reduce (only lane 0 holds nonzero) then atomic
    #pragma unroll
    for (int off = 32; off; off >>= 1) {
        local_loss += __shfl_xor(local_loss, off);
        local_cnt  += __shfl_xor(local_cnt, off);
    }
    if (lane == 0) {
        atomicAdd(&ws[WS_ACC + 0], local_loss);
        atomicAdd(&ws[WS_ACC + 1], local_cnt);
    }
}

__global__ void finish_kernel(const float* __restrict__ ws, float* __restrict__ out) {
    out[BB*SS] = ws[WS_ACC + 0] / fmaxf(ws[WS_ACC + 1], 1.0f);
}

extern "C" void kernel_launch(void* const* d_in, const int* in_sizes, int n_in,
                              void* d_out, int out_size, void* d_ws, size_t ws_size,
                              hipStream_t stream) {
    const int*   q_data    = (const int*)d_in[0];
    const int*   qa_data   = (const int*)d_in[1];
    const float* target    = (const float*)d_in[2];
    const float* q_embed   = (const float*)d_in[3];
    const float* qa_embed  = (const float*)d_in[4];
    const float* key_mem   = (const float*)d_in[5];
    const float* init_mv   = (const float*)d_in[6];
    const float* erase_w   = (const float*)d_in[7];
    const float* erase_b   = (const float*)d_in[8];
    const float* add_w     = (const float*)d_in[9];
    const float* add_b     = (const float*)d_in[10];
    const float* input_w   = (const float*)d_in[11];
    const float* input_b   = (const float*)d_in[12];
    const float* read_w    = (const float*)d_in[13];
    const float* read_b    = (const float*)d_in[14];
    const float* predict_w = (const float*)d_in[15];
    const float* predict_b = (const float*)d_in[16];

    float* ws  = (float*)d_ws;
    float* out = (float*)d_out;

    hipLaunchKernelGGL(prep_kernel, dim3(256), dim3(256), 0, stream,
                       erase_w, add_w, key_mem, input_w, read_w, ws);
    hipLaunchKernelGGL(dkvmn_kernel, dim3(BB), dim3(DV), 0, stream,
                       q_data, qa_data, target, q_embed, qa_embed, init_mv,
                       erase_b, add_b, input_b, read_b, predict_w, predict_b,
                       ws, out);
    hipLaunchKernelGGL(finish_kernel, dim3(1), dim3(1), 0, stream, ws, out);
}

// Round 2
// 1984.672 us; speedup vs baseline: 2.2774x; 2.2774x over previous
//
#include <hip/hip_runtime.h>
#include <hip/hip_bf16.h>
#include <math.h>

#define BB 512
#define SS 512
#define MM 64
#define DK 128
#define DV 256
#define DF 128
#define CHUNK 16
#define NCHUNK (SS/CHUNK)

typedef __attribute__((ext_vector_type(8))) short s8v;   // 8 bf16 = 4 VGPRs
typedef __attribute__((ext_vector_type(4))) float f4v;   // MFMA accumulator

#define MFMA16(a,b,c) __builtin_amdgcn_mfma_f32_16x16x32_bf16((a),(b),(c),0,0,0)

// ---- workspace layout ----
// floats [0..15]: loss accumulators.  bf16 region starts at ws+16 floats (64B aligned):
//   EAP [131072] : erase|add packed B-frags, N=512 (cols 0-255 erase, 256-511 add), K=256
//   KTP [  8192] : key    packed, N=64,  K=128
//   ITP [ 16384] : input  packed, N=128, K=128
//   RTP [ 49152] : read   packed, N=128, K=384
// packed flat index: ((nf*NKS + ks)*64 + lane)*8 + e  ;  value = B[ks*32+(lane>>4)*8+e][nf*16+(lane&15)]
#define EAP_OFF 0
#define KTP_OFF 131072
#define ITP_OFF 139264
#define RTP_OFF 155648

__device__ __host__ __forceinline__ unsigned short f2bf(float x) {
    union { float f; unsigned u; } v; v.f = x;
    unsigned r = v.u + 0x7fffu + ((v.u >> 16) & 1u);
    return (unsigned short)(r >> 16);
}

__global__ void prep_kernel(const float* __restrict__ ew, const float* __restrict__ aw,
                            const float* __restrict__ km, const float* __restrict__ iw,
                            const float* __restrict__ rw, float* __restrict__ wsf) {
    int tid = blockIdx.x * 256 + threadIdx.x;
    int stride = gridDim.x * 256;
    if (tid < 2) wsf[tid] = 0.0f;
    unsigned short* bp = (unsigned short*)(wsf + 16);

    for (int i = tid; i < 131072; i += stride) {           // EAP: nf<32, ks<8
        int e = i & 7, l = (i >> 3) & 63, ks = (i >> 9) & 7, nf = i >> 12;
        int k = ks*32 + (l >> 4)*8 + e;
        int n = nf*16 + (l & 15);
        float v = (n < 256) ? ew[n*DV + k] : aw[(n-256)*DV + k];
        bp[EAP_OFF + i] = f2bf(v);
    }
    for (int i = tid; i < 8192; i += stride) {             // KTP: nf<4, ks<4
        int e = i & 7, l = (i >> 3) & 63, ks = (i >> 9) & 3, nf = i >> 11;
        int k = ks*32 + (l >> 4)*8 + e;
        int m = nf*16 + (l & 15);
        bp[KTP_OFF + i] = f2bf(km[m*DK + k]);
    }
    for (int i = tid; i < 16384; i += stride) {            // ITP: nf<8, ks<4
        int e = i & 7, l = (i >> 3) & 63, ks = (i >> 9) & 3, nf = i >> 11;
        int k = ks*32 + (l >> 4)*8 + e;
        int f = nf*16 + (l & 15);
        bp[ITP_OFF + i] = f2bf(iw[f*DK + k]);
    }
    for (int i = tid; i < 49152; i += stride) {            // RTP: nf<8, ks<12
        int e = i & 7, l = (i >> 3) & 63, g = i >> 9;      // g = nf*12+ks
        int ks = g % 12, nf = g / 12;
        int j = ks*32 + (l >> 4)*8 + e;
        int f = nf*16 + (l & 15);
        bp[RTP_OFF + i] = f2bf(rw[f*(DV+DF) + j]);
    }
}

__device__ __forceinline__ float sigmoidf_(float x) { return 1.0f / (1.0f + __expf(-x)); }
__device__ __forceinline__ float fast_tanh(float x) {
    float e = __expf(2.0f * x);
    return 1.0f - 2.0f / (e + 1.0f);
}

// LDS layout (byte offsets into smem[61824], all regions 128B-aligned):
//  qa16  [16][256] bf16 swizzled        @ 0      (8192)
//  q16   [16][128] bf16 swizzled        @ 8192   (4096)
//  cat16 [16][384] bf16 swizzled        @ 12288  (12288)   cols 0-255 = read, 256-383 = ie
//  sc_f  [16][66]  f32                  @ 24576  (4224)    scores -> softmax w
//  er_f  [16][258] f32                  @ 28800  (16512)   (aliased by rce_f [16][130])
//  ad_f  [16][258] f32                  @ 45312  (16512)
__launch_bounds__(256, 2)
__global__ void dkvmn_kernel(const int* __restrict__ q_data, const int* __restrict__ qa_data,
                             const float* __restrict__ target,
                             const float* __restrict__ q_embed, const float* __restrict__ qa_embed,
                             const float* __restrict__ init_mv,
                             const float* __restrict__ erase_b, const float* __restrict__ add_b,
                             const float* __restrict__ input_b, const float* __restrict__ read_b,
                             const float* __restrict__ predict_w, const float* __restrict__ predict_b,
                             float* __restrict__ ws, float* __restrict__ out) {
    __shared__ __align__(16) char smem[61824];
    char*  qa16  = smem;
    char*  q16   = smem + 8192;
    char*  cat16 = smem + 12288;
    float* sc_f  = (float*)(smem + 24576);
    float* er_f  = (float*)(smem + 28800);
    float* ad_f  = (float*)(smem + 45312);
    float* rce_f = (float*)(smem + 28800);   // alias er_f (dead by then)

    const int b    = blockIdx.x;
    const int tid  = threadIdx.x;
    const int lane = tid & 63;
    const int wave = tid >> 6;
    const int arow = lane & 15;      // MFMA A/B lane row/col
    const int ag   = lane >> 4;      // MFMA k-group / C row-group

    const unsigned short* wsb = (const unsigned short*)(ws + 16);
    const s8v* eap = (const s8v*)(wsb + EAP_OFF);
    const s8v* ktp = (const s8v*)(wsb + KTP_OFF);
    const s8v* itp = (const s8v*)(wsb + ITP_OFF);
    const s8v* rtp = (const s8v*)(wsb + RTP_OFF);

    // Mv state in registers: thread owns column d = tid
    float mv[MM];
    #pragma unroll
    for (int m = 0; m < MM; ++m) mv[m] = init_mv[m*DV + tid];

    // per-wave bias fragments
    float biasEA[8];
    #pragma unroll
    for (int i = 0; i < 8; ++i) {
        int n = (wave*8 + i)*16 + arow;
        biasEA[i] = (n < 256) ? erase_b[n] : add_b[n - 256];
    }
    float ib[2], rb[2];
    #pragma unroll
    for (int i = 0; i < 2; ++i) {
        int f = (wave*2 + i)*16 + arow;
        ib[i] = input_b[f];
        rb[i] = read_b[f];
    }
    const float pw_lo = predict_w[lane];
    const float pw_hi = predict_w[lane + 64];
    float local_loss = 0.0f, local_cnt = 0.0f;

    for (int c = 0; c < NCHUNK; ++c) {
        const int s0 = c * CHUNK;

        // ---- gather embeddings -> bf16 LDS (XOR-swizzled rows) ----
        for (int i = tid; i < 16*64; i += 256) {            // q: [16][128], pairs
            int r = i >> 6, cp = i & 63;
            int idx = q_data[b*SS + s0 + r];
            float2 v = *(const float2*)(q_embed + idx*DK + cp*2);
            unsigned pk = (unsigned)f2bf(v.x) | ((unsigned)f2bf(v.y) << 16);
            int byte = (r*256 + cp*4) ^ ((r & 7) << 4);
            *(unsigned*)(q16 + byte) = pk;
        }
        for (int i = tid; i < 16*128; i += 256) {           // qa: [16][256], pairs
            int r = i >> 7, cp = i & 127;
            int idx = qa_data[b*SS + s0 + r];
            float2 v = *(const float2*)(qa_embed + idx*DV + cp*2);
            unsigned pk = (unsigned)f2bf(v.x) | ((unsigned)f2bf(v.y) << 16);
            int byte = (r*512 + cp*4) ^ ((r & 7) << 4);
            *(unsigned*)(qa16 + byte) = pk;
        }
        __syncthreads();   // B1: gather done; also protects er/rce alias vs prev pred

        // ---- scores MFMA: [16][128] x [128][64] ; wave owns 16 cols ----
        {
            f4v cc = {0.f,0.f,0.f,0.f};
            #pragma unroll
            for (int ks = 0; ks < 4; ++ks) {
                int byte = (arow*256 + ks*64 + ag*16) ^ ((arow & 7) << 4);
                s8v a = *(const s8v*)(q16 + byte);
                cc = MFMA16(a, ktp[(wave*4 + ks)*64 + lane], cc);
            }
            int m = wave*16 + arow;
            #pragma unroll
            for (int r = 0; r < 4; ++r) sc_f[(ag*4 + r)*66 + m] = cc[r];
        }

        // ---- ie MFMA: [16][128] x [128][128] -> tanh -> cat16[:,256:384] ----
        #pragma unroll
        for (int i = 0; i < 2; ++i) {
            f4v cc = {0.f,0.f,0.f,0.f};
            #pragma unroll
            for (int ks = 0; ks < 4; ++ks) {
                int byte = (arow*256 + ks*64 + ag*16) ^ ((arow & 7) << 4);
                s8v a = *(const s8v*)(q16 + byte);
                cc = MFMA16(a, itp[((wave*2 + i)*4 + ks)*64 + lane], cc);
            }
            int f = (wave*2 + i)*16 + arow;
            #pragma unroll
            for (int r = 0; r < 4; ++r) {
                int row = ag*4 + r;
                float v = fast_tanh(cc[r] + ib[i]);
                int byte = (row*768 + (256 + f)*2) ^ ((row & 7) << 4);
                *(unsigned short*)(cat16 + byte) = f2bf(v);
            }
        }

        // ---- erase|add MFMA: [16][256] x [256][512] ; wave owns 128 cols ----
        {
            s8v af[8];
            #pragma unroll
            for (int ks = 0; ks < 8; ++ks) {
                int byte = (arow*512 + ks*64 + ag*16) ^ ((arow & 7) << 4);
                af[ks] = *(const s8v*)(qa16 + byte);
            }
            #pragma unroll
            for (int i = 0; i < 8; ++i) {
                const s8v* bpp = eap + (wave*8 + i)*512 + lane;
                f4v cc = {0.f,0.f,0.f,0.f};
                #pragma unroll
                for (int ks = 0; ks < 8; ++ks) cc = MFMA16(af[ks], bpp[ks*64], cc);
                int n = (wave*8 + i)*16 + arow;
                #pragma unroll
                for (int r = 0; r < 4; ++r) {
                    int row = ag*4 + r;
                    float v = cc[r] + biasEA[i];
                    if (n < 256) er_f[row*258 + n]        = sigmoidf_(v);
                    else         ad_f[row*258 + (n-256)]  = fast_tanh(v);
                }
            }
        }
        __syncthreads();   // B2: scores/er/ad complete

        // ---- softmax rows (in place in sc_f) ----
        #pragma unroll
        for (int k = 0; k < 4; ++k) {
            int rr = wave*4 + k;
            float sc = sc_f[rr*66 + lane];
            float mx = sc;
            #pragma unroll
            for (int off = 32; off; off >>= 1) mx = fmaxf(mx, __shfl_xor(mx, off));
            float e = __expf(sc - mx);
            float sum = e;
            #pragma unroll
            for (int off = 32; off; off >>= 1) sum += __shfl_xor(sum, off);
            sc_f[rr*66 + lane] = e / sum;
        }
        __syncthreads();   // B3: softmax w ready

        // ---- sequential recurrence; Mv in registers; read -> cat16[:,0:256] ----
        for (int s = 0; s < CHUNK; ++s) {
            float e = er_f[s*258 + tid];
            float a = ad_f[s*258 + tid];
            const float* wrow = sc_f + s*66;
            float r0 = 0.f, r1 = 0.f, r2 = 0.f, r3 = 0.f;
            #pragma unroll
            for (int m = 0; m < MM; m += 4) {
                float w0 = wrow[m], w1 = wrow[m+1], w2 = wrow[m+2], w3 = wrow[m+3];
                r0 = fmaf(w0, mv[m  ], r0); mv[m  ] = fmaf(w0, fmaf(-mv[m  ], e, a), mv[m  ]);
                r1 = fmaf(w1, mv[m+1], r1); mv[m+1] = fmaf(w1, fmaf(-mv[m+1], e, a), mv[m+1]);
                r2 = fmaf(w2, mv[m+2], r2); mv[m+2] = fmaf(w2, fmaf(-mv[m+2], e, a), mv[m+2]);
                r3 = fmaf(w3, mv[m+3], r3); mv[m+3] = fmaf(w3, fmaf(-mv[m+3], e, a), mv[m+3]);
            }
            float rd = (r0 + r1) + (r2 + r3);
            int byte = (s*768 + tid*2) ^ ((s & 7) << 4);
            *(unsigned short*)(cat16 + byte) = f2bf(rd);
        }
        __syncthreads();   // B4: cat complete

        // ---- rce MFMA: [16][384] x [384][128] -> tanh -> rce_f ----
        #pragma unroll
        for (int i = 0; i < 2; ++i) {
            f4v cc = {0.f,0.f,0.f,0.f};
            #pragma unroll
            for (int ks = 0; ks < 12; ++ks) {
                int byte = (arow*768 + ks*64 + ag*16) ^ ((arow & 7) << 4);
                s8v a = *(const s8v*)(cat16 + byte);
                cc = MFMA16(a, rtp[((wave*2 + i)*12 + ks)*64 + lane], cc);
            }
            int f = (wave*2 + i)*16 + arow;
            #pragma unroll
            for (int r = 0; r < 4; ++r)
                rce_f[(ag*4 + r)*130 + f] = fast_tanh(cc[r] + rb[i]);
        }
        __syncthreads();   // B5: rce ready

        // ---- pred + outputs + loss: wave per row ----
        #pragma unroll
        for (int k = 0; k < 4; ++k) {
            int r = wave*4 + k;
            float p = fmaf(pw_lo, rce_f[r*130 + lane], pw_hi * rce_f[r*130 + 64 + lane]);
            #pragma unroll
            for (int off = 32; off; off >>= 1) p += __shfl_xor(p, off);
            if (lane == 0) {
                p += predict_b[0];
                int gi = b*SS + s0 + r;
                float t = target[gi];
                bool mask = t >= 0.0f;
                out[gi] = sigmoidf_(p);
                float pm = mask ? p : 0.0f;
                out[BB*SS + 1 + gi] = sigmoidf_(pm);
                out[2*BB*SS + 1 + gi] = mask ? t : 0.0f;
                if (mask) {
                    float bce = fmaxf(p, 0.0f) - p*t + log1pf(__expf(-fabsf(p)));
                    local_loss += bce;
                    local_cnt  += 1.0f;
                }
            }
        }
        __syncthreads();   // B6: pred done before next gather overwrites LDS
    }

    #pragma unroll
    for (int off = 32; off; off >>= 1) {
        local_loss += __shfl_xor(local_loss, off);
        local_cnt  += __shfl_xor(local_cnt, off);
    }
    if (lane == 0) {
        atomicAdd(&ws[0], local_loss);
        atomicAdd(&ws[1], local_cnt);
    }
}

__global__ void finish_kernel(const float* __restrict__ ws, float* __restrict__ out) {
    out[BB*SS] = ws[0] / fmaxf(ws[1], 1.0f);
}

extern "C" void kernel_launch(void* const* d_in, const int* in_sizes, int n_in,
                              void* d_out, int out_size, void* d_ws, size_t ws_size,
                              hipStream_t stream) {
    const int*   q_data    = (const int*)d_in[0];
    const int*   qa_data   = (const int*)d_in[1];
    const float* target    = (const float*)d_in[2];
    const float* q_embed   = (const float*)d_in[3];
    const float* qa_embed  = (const float*)d_in[4];
    const float* key_mem   = (const float*)d_in[5];
    const float* init_mv   = (const float*)d_in[6];
    const float* erase_w   = (const float*)d_in[7];
    const float* add_b     = (const float*)d_in[10];
    const float* erase_b   = (const float*)d_in[8];
    const float* add_w     = (const float*)d_in[9];
    const float* input_w   = (const float*)d_in[11];
    const float* input_b   = (const float*)d_in[12];
    const float* read_w    = (const float*)d_in[13];
    const float* read_b    = (const float*)d_in[14];
    const float* predict_w = (const float*)d_in[15];
    const float* predict_b = (const float*)d_in[16];

    float* ws  = (float*)d_ws;
    float* out = (float*)d_out;

    hipLaunchKernelGGL(prep_kernel, dim3(128), dim3(256), 0, stream,
                       erase_w, add_w, key_mem, input_w, read_w, ws);
    hipLaunchKernelGGL(dkvmn_kernel, dim3(BB), dim3(DV), 0, stream,
                       q_data, qa_data, target, q_embed, qa_embed, init_mv,
                       erase_b, add_b, input_b, read_b, predict_w, predict_b,
                       ws, out);
    hipLaunchKernelGGL(finish_kernel, dim3(1), dim3(1), 0, stream, ws, out);
}

// Round 3
// 1431.963 us; speedup vs baseline: 3.1565x; 1.3860x over previous
//
#include <hip/hip_runtime.h>
#include <hip/hip_bf16.h>
#include <math.h>

#define BB 512
#define SS 512
#define MM 64
#define DK 128
#define DV 256
#define DF 128
#define CHUNK 16
#define NCHUNK (SS/CHUNK)

typedef __attribute__((ext_vector_type(8))) short s8v;   // 8 bf16 = 4 VGPRs
typedef __attribute__((ext_vector_type(4))) float f4v;   // MFMA accumulator

#define MFMA16(a,b,c) __builtin_amdgcn_mfma_f32_16x16x32_bf16((a),(b),(c),0,0,0)

// ---- workspace layout ----
// floats [0..15]: loss accumulators.  u16 region at ws+16 floats:
//   EAP  : erase|add packed B-frags, N=512 (0-255 erase, 256-511 add), K=256
//   KTP  : key    packed, N=64,  K=128
//   ITP  : input  packed, N=128, K=128
//   RTP  : read   packed, N=128, K=384
//   QTAB : q_embed  as bf16 [10001][128]
//   QATAB: qa_embed as bf16 [20001][256]
#define EAP_OFF 0
#define KTP_OFF 131072
#define ITP_OFF 139264
#define RTP_OFF 155648
#define QTAB_OFF 204800
#define QATAB_OFF (QTAB_OFF + 10001*DK)          // 1484928
#define WS_U16_TOTAL (QATAB_OFF + 20001*DV)      // 6605184
#define WS_NEED_BYTES (64 + 2*(size_t)WS_U16_TOTAL)

__device__ __forceinline__ unsigned short f2bf(float x) {
    union { float f; unsigned u; } v; v.f = x;
    unsigned r = v.u + 0x7fffu + ((v.u >> 16) & 1u);
    return (unsigned short)(r >> 16);
}
__device__ __forceinline__ float bf2f(unsigned short h) {
    union { unsigned u; float f; } v; v.u = ((unsigned)h) << 16;
    return v.f;
}
__device__ __forceinline__ float sigmoidf_(float x) { return 1.0f / (1.0f + __expf(-x)); }
__device__ __forceinline__ float fast_tanh(float x) {
    float e = __expf(2.0f * x);
    return 1.0f - 2.0f / (e + 1.0f);
}

__global__ void prep_kernel(const float* __restrict__ ew, const float* __restrict__ aw,
                            const float* __restrict__ km, const float* __restrict__ iw,
                            const float* __restrict__ rw,
                            const float* __restrict__ qe, const float* __restrict__ qae,
                            int do_tab, float* __restrict__ wsf) {
    int tid = blockIdx.x * 256 + threadIdx.x;
    int stride = gridDim.x * 256;
    if (tid < 2) wsf[tid] = 0.0f;
    unsigned short* bp = (unsigned short*)(wsf + 16);

    for (int i = tid; i < 131072; i += stride) {           // EAP: nf<32, ks<8
        int e = i & 7, l = (i >> 3) & 63, ks = (i >> 9) & 7, nf = i >> 12;
        int k = ks*32 + (l >> 4)*8 + e;
        int n = nf*16 + (l & 15);
        float v = (n < 256) ? ew[n*DV + k] : aw[(n-256)*DV + k];
        bp[EAP_OFF + i] = f2bf(v);
    }
    for (int i = tid; i < 8192; i += stride) {             // KTP: nf<4, ks<4
        int e = i & 7, l = (i >> 3) & 63, ks = (i >> 9) & 3, nf = i >> 11;
        int k = ks*32 + (l >> 4)*8 + e;
        int m = nf*16 + (l & 15);
        bp[KTP_OFF + i] = f2bf(km[m*DK + k]);
    }
    for (int i = tid; i < 16384; i += stride) {            // ITP: nf<8, ks<4
        int e = i & 7, l = (i >> 3) & 63, ks = (i >> 9) & 3, nf = i >> 11;
        int k = ks*32 + (l >> 4)*8 + e;
        int f = nf*16 + (l & 15);
        bp[ITP_OFF + i] = f2bf(iw[f*DK + k]);
    }
    for (int i = tid; i < 49152; i += stride) {            // RTP: nf<8, ks<12
        int e = i & 7, l = (i >> 3) & 63, g = i >> 9;
        int ks = g % 12, nf = g / 12;
        int j = ks*32 + (l >> 4)*8 + e;
        int f = nf*16 + (l & 15);
        bp[RTP_OFF + i] = f2bf(rw[f*(DV+DF) + j]);
    }
    if (do_tab) {
        for (int i = tid; i < 10001*DK; i += stride) bp[QTAB_OFF + i]  = f2bf(qe[i]);
        for (int i = tid; i < 20001*DV; i += stride) bp[QATAB_OFF + i] = f2bf(qae[i]);
    }
}

// LDS (byte offsets into smem[54272]):
//  qa16  [16][512B] bf16 swizzled   @ 0
//  q16   [16][256B] bf16 swizzled   @ 8192
//  cat16 [16][768B] bf16 swizzled   @ 12288   cols 0-255 read, 256-383 ie
//  sc_f  [16][68] f32               @ 24576   scores -> softmax w
//  er16  [16][264] bf16             @ 28928   (aliased by rce_f [16][132] f32)
//  ad16  [16][264] bf16             @ 37376
//  rdp   [16][264] bf16             @ 45824   half1 read-partials
template<int TAB16>
__launch_bounds__(512, 4)
__global__ void dkvmn_kernel(const int* __restrict__ q_data, const int* __restrict__ qa_data,
                             const float* __restrict__ target,
                             const float* __restrict__ q_embed, const float* __restrict__ qa_embed,
                             const float* __restrict__ init_mv,
                             const float* __restrict__ erase_b, const float* __restrict__ add_b,
                             const float* __restrict__ input_b, const float* __restrict__ read_b,
                             const float* __restrict__ predict_w, const float* __restrict__ predict_b,
                             float* __restrict__ ws, float* __restrict__ out) {
    __shared__ __align__(128) char smem[54272];
    char*           qa16 = smem;
    char*           q16  = smem + 8192;
    char*           cat16= smem + 12288;
    float*          sc_f = (float*)(smem + 24576);
    unsigned short* er16 = (unsigned short*)(smem + 28928);
    unsigned short* ad16 = (unsigned short*)(smem + 37376);
    unsigned short* rdp  = (unsigned short*)(smem + 45824);
    float*          rce_f= (float*)(smem + 28928);   // alias er16 (dead after B4)

    const int b    = blockIdx.x;
    const int tid  = threadIdx.x;
    const int lane = tid & 63;
    const int wave = tid >> 6;       // 0..7
    const int arow = lane & 15;
    const int ag   = lane >> 4;
    const int d    = tid & 255;
    const int half = tid >> 8;

    const unsigned short* wsb = (const unsigned short*)(ws + 16);
    const s8v* eap = (const s8v*)(wsb + EAP_OFF);
    const s8v* ktp = (const s8v*)(wsb + KTP_OFF);
    const s8v* itp = (const s8v*)(wsb + ITP_OFF);
    const s8v* rtp = (const s8v*)(wsb + RTP_OFF);
    const unsigned short* qtab  = wsb + QTAB_OFF;
    const unsigned short* qatab = wsb + QATAB_OFF;

    // Mv state: thread (d, half) owns mv[m], m = half*32 + i
    float mv[32];
    #pragma unroll
    for (int i = 0; i < 32; ++i) mv[i] = init_mv[(half*32 + i)*DV + d];

    float biasEA[4];
    #pragma unroll
    for (int i = 0; i < 4; ++i) {
        int n = (wave*4 + i)*16 + arow;
        biasEA[i] = (n < 256) ? erase_b[n] : add_b[n - 256];
    }
    float ib0 = 0.f, ib1 = 0.f;
    if (wave >= 4) {
        ib0 = input_b[((wave-4)*2 + 0)*16 + arow];
        ib1 = input_b[((wave-4)*2 + 1)*16 + arow];
    }
    const float rb    = read_b[wave*16 + arow];
    const float pw_lo = predict_w[lane];
    const float pw_hi = predict_w[lane + 64];

    // ---- gather pipeline state ----
    const int base = b * SS;
    const int qc  = tid & 31;   // q col-unit (4 bf16)
    const int qr  = tid >> 5;   // q row
    const int ac  = tid & 63;   // qa col-unit
    const int ar0 = tid >> 6;   // qa rows ar0, ar0+8
    int iq, ia0, ia1, jq, ja0, ja1;
    ushort4 pq, pa0, pa1;
    float4  fq, fa0, fa1;

    auto loadidx = [&](int cc, int& x, int& y0, int& y1) {
        x  = q_data [base + cc*CHUNK + qr];
        y0 = qa_data[base + cc*CHUNK + ar0];
        y1 = qa_data[base + cc*CHUNK + ar0 + 8];
    };
    auto loadrows = [&]() {
        if constexpr (TAB16) {
            pq  = *(const ushort4*)(qtab  + iq *DK + qc*4);
            pa0 = *(const ushort4*)(qatab + ia0*DV + ac*4);
            pa1 = *(const ushort4*)(qatab + ia1*DV + ac*4);
        } else {
            fq  = *(const float4*)(q_embed  + iq *DK + qc*4);
            fa0 = *(const float4*)(qa_embed + ia0*DV + ac*4);
            fa1 = *(const float4*)(qa_embed + ia1*DV + ac*4);
        }
    };
    auto storerows = [&]() {
        ushort4 vq, v0, v1;
        if constexpr (TAB16) { vq = pq; v0 = pa0; v1 = pa1; }
        else {
            vq.x = f2bf(fq.x);  vq.y = f2bf(fq.y);  vq.z = f2bf(fq.z);  vq.w = f2bf(fq.w);
            v0.x = f2bf(fa0.x); v0.y = f2bf(fa0.y); v0.z = f2bf(fa0.z); v0.w = f2bf(fa0.w);
            v1.x = f2bf(fa1.x); v1.y = f2bf(fa1.y); v1.z = f2bf(fa1.z); v1.w = f2bf(fa1.w);
        }
        *(ushort4*)(q16  + ((qr*256 + qc*8)      ^ ((qr  & 7) << 4))) = vq;
        *(ushort4*)(qa16 + ((ar0*512 + ac*8)     ^ ((ar0 & 7) << 4))) = v0;
        *(ushort4*)(qa16 + (((ar0+8)*512 + ac*8) ^ (((ar0+8) & 7) << 4))) = v1;
    };

    loadidx(0, iq, ia0, ia1);
    loadrows();
    loadidx(1, jq, ja0, ja1);

    float local_loss = 0.0f, local_cnt = 0.0f;

    for (int c = 0; c < NCHUNK; ++c) {
        storerows();
        __syncthreads();                               // B1: gathers in LDS
        iq = jq; ia0 = ja0; ia1 = ja1;
        if (c + 1 < NCHUNK) loadrows();                // prefetch next chunk rows
        { int c2 = (c + 2 < NCHUNK) ? c + 2 : NCHUNK - 1; loadidx(c2, jq, ja0, ja1); }

        // ---- scores (waves 0-3) | ie (waves 4-7) ----
        if (wave < 4) {
            f4v cc = {0.f,0.f,0.f,0.f};
            #pragma unroll
            for (int ks = 0; ks < 4; ++ks) {
                s8v a = *(const s8v*)(q16 + ((arow*256 + ks*64 + ag*16) ^ ((arow & 7) << 4)));
                cc = MFMA16(a, ktp[(wave*4 + ks)*64 + lane], cc);
            }
            int m = wave*16 + arow;
            #pragma unroll
            for (int r = 0; r < 4; ++r) sc_f[(ag*4 + r)*68 + m] = cc[r];
        } else {
            s8v aq[4];
            #pragma unroll
            for (int ks = 0; ks < 4; ++ks)
                aq[ks] = *(const s8v*)(q16 + ((arow*256 + ks*64 + ag*16) ^ ((arow & 7) << 4)));
            #pragma unroll
            for (int i = 0; i < 2; ++i) {
                int nf = (wave - 4)*2 + i;
                f4v cc = {0.f,0.f,0.f,0.f};
                #pragma unroll
                for (int ks = 0; ks < 4; ++ks)
                    cc = MFMA16(aq[ks], itp[(nf*4 + ks)*64 + lane], cc);
                int f = nf*16 + arow;
                float bias = i ? ib1 : ib0;
                #pragma unroll
                for (int r = 0; r < 4; ++r) {
                    int row = ag*4 + r;
                    *(unsigned short*)(cat16 + ((row*768 + (256 + f)*2) ^ ((row & 7) << 4))) =
                        f2bf(fast_tanh(cc[r] + bias));
                }
            }
        }

        // ---- erase|add MFMA (all waves): wave owns 4 nf tiles ----
        {
            s8v af[8];
            #pragma unroll
            for (int ks = 0; ks < 8; ++ks)
                af[ks] = *(const s8v*)(qa16 + ((arow*512 + ks*64 + ag*16) ^ ((arow & 7) << 4)));
            #pragma unroll
            for (int i = 0; i < 4; ++i) {
                const s8v* bp2 = eap + ((wave*4 + i)*8)*64 + lane;
                f4v cc = {0.f,0.f,0.f,0.f};
                #pragma unroll
                for (int ks = 0; ks < 8; ++ks) cc = MFMA16(af[ks], bp2[ks*64], cc);
                int n = (wave*4 + i)*16 + arow;
                if (wave < 4) {
                    #pragma unroll
                    for (int r = 0; r < 4; ++r)
                        er16[(ag*4 + r)*264 + n] = f2bf(sigmoidf_(cc[r] + biasEA[i]));
                } else {
                    #pragma unroll
                    for (int r = 0; r < 4; ++r)
                        ad16[(ag*4 + r)*264 + (n - 256)] = f2bf(fast_tanh(cc[r] + biasEA[i]));
                }
            }
        }
        __syncthreads();                               // B2

        // ---- softmax: 2 rows per wave ----
        #pragma unroll
        for (int k = 0; k < 2; ++k) {
            int rr = wave*2 + k;
            float sc = sc_f[rr*68 + lane];
            float mx = sc;
            #pragma unroll
            for (int off = 32; off; off >>= 1) mx = fmaxf(mx, __shfl_xor(mx, off));
            float e = __expf(sc - mx);
            float sum = e;
            #pragma unroll
            for (int off = 32; off; off >>= 1) sum += __shfl_xor(sum, off);
            sc_f[rr*68 + lane] = e / sum;
        }
        __syncthreads();                               // B3

        // ---- recurrence: thread (d,half) owns 32 m-slots ----
        for (int s = 0; s < CHUNK; ++s) {
            float e = bf2f(er16[s*264 + d]);
            float a = bf2f(ad16[s*264 + d]);
            const float4* wr4 = (const float4*)(sc_f + s*68 + half*32);
            float r0 = 0.f, r1 = 0.f, r2 = 0.f, r3 = 0.f;
            #pragma unroll
            for (int j = 0; j < 8; ++j) {
                float4 w = wr4[j];
                r0 = fmaf(w.x, mv[j*4+0], r0); mv[j*4+0] = fmaf(w.x, fmaf(-mv[j*4+0], e, a), mv[j*4+0]);
                r1 = fmaf(w.y, mv[j*4+1], r1); mv[j*4+1] = fmaf(w.y, fmaf(-mv[j*4+1], e, a), mv[j*4+1]);
                r2 = fmaf(w.z, mv[j*4+2], r2); mv[j*4+2] = fmaf(w.z, fmaf(-mv[j*4+2], e, a), mv[j*4+2]);
                r3 = fmaf(w.w, mv[j*4+3], r3); mv[j*4+3] = fmaf(w.w, fmaf(-mv[j*4+3], e, a), mv[j*4+3]);
            }
            float rd = (r0 + r1) + (r2 + r3);
            if (half == 0) {
                *(unsigned short*)(cat16 + ((s*768 + d*2) ^ ((s & 7) << 4))) = f2bf(rd);
            } else {
                rdp[s*264 + d] = f2bf(rd);
            }
        }
        __syncthreads();                               // B4

        // ---- combine read halves (half0 waves) ----
        if (half == 0) {
            #pragma unroll
            for (int s = 0; s < CHUNK; ++s) {
                unsigned short* p = (unsigned short*)(cat16 + ((s*768 + d*2) ^ ((s & 7) << 4)));
                *p = f2bf(bf2f(*p) + bf2f(rdp[s*264 + d]));
            }
        }
        __syncthreads();                               // B5

        // ---- rce MFMA: wave owns nf = wave, K=384 ----
        {
            f4v cc = {0.f,0.f,0.f,0.f};
            #pragma unroll
            for (int ks = 0; ks < 12; ++ks) {
                s8v a = *(const s8v*)(cat16 + ((arow*768 + ks*64 + ag*16) ^ ((arow & 7) << 4)));
                cc = MFMA16(a, rtp[(wave*12 + ks)*64 + lane], cc);
            }
            int f = wave*16 + arow;
            #pragma unroll
            for (int r = 0; r < 4; ++r)
                rce_f[(ag*4 + r)*132 + f] = fast_tanh(cc[r] + rb);
        }
        __syncthreads();                               // B6

        // ---- pred + outputs + loss: 2 rows per wave ----
        #pragma unroll
        for (int k = 0; k < 2; ++k) {
            int r = wave*2 + k;
            float p = fmaf(pw_lo, rce_f[r*132 + lane], pw_hi * rce_f[r*132 + 64 + lane]);
            #pragma unroll
            for (int off = 32; off; off >>= 1) p += __shfl_xor(p, off);
            if (lane == 0) {
                p += predict_b[0];
                int gi = b*SS + c*CHUNK + r;
                float t = target[gi];
                bool mask = t >= 0.0f;
                out[gi] = sigmoidf_(p);
                float pm = mask ? p : 0.0f;
                out[BB*SS + 1 + gi] = sigmoidf_(pm);
                out[2*BB*SS + 1 + gi] = mask ? t : 0.0f;
                if (mask) {
                    local_loss += fmaxf(p, 0.0f) - p*t + log1pf(__expf(-fabsf(p)));
                    local_cnt  += 1.0f;
                }
            }
        }
        // no barrier: next storerows touches only q16/qa16 (readers done at B2)
    }

    #pragma unroll
    for (int off = 32; off; off >>= 1) {
        local_loss += __shfl_xor(local_loss, off);
        local_cnt  += __shfl_xor(local_cnt, off);
    }
    if (lane == 0) {
        atomicAdd(&ws[0], local_loss);
        atomicAdd(&ws[1], local_cnt);
    }
}

__global__ void finish_kernel(const float* __restrict__ ws, float* __restrict__ out) {
    out[BB*SS] = ws[0] / fmaxf(ws[1], 1.0f);
}

extern "C" void kernel_launch(void* const* d_in, const int* in_sizes, int n_in,
                              void* d_out, int out_size, void* d_ws, size_t ws_size,
                              hipStream_t stream) {
    const int*   q_data    = (const int*)d_in[0];
    const int*   qa_data   = (const int*)d_in[1];
    const float* target    = (const float*)d_in[2];
    const float* q_embed   = (const float*)d_in[3];
    const float* qa_embed  = (const float*)d_in[4];
    const float* key_mem   = (const float*)d_in[5];
    const float* init_mv   = (const float*)d_in[6];
    const float* erase_w   = (const float*)d_in[7];
    const float* erase_b   = (const float*)d_in[8];
    const float* add_w     = (const float*)d_in[9];
    const float* add_b     = (const float*)d_in[10];
    const float* input_w   = (const float*)d_in[11];
    const float* input_b   = (const float*)d_in[12];
    const float* read_w    = (const float*)d_in[13];
    const float* read_b    = (const float*)d_in[14];
    const float* predict_w = (const float*)d_in[15];
    const float* predict_b = (const float*)d_in[16];

    float* ws  = (float*)d_ws;
    float* out = (float*)d_out;

    int tab = (ws_size >= WS_NEED_BYTES) ? 1 : 0;

    hipLaunchKernelGGL(prep_kernel, dim3(1024), dim3(256), 0, stream,
                       erase_w, add_w, key_mem, input_w, read_w, q_embed, qa_embed, tab, ws);
    if (tab) {
        hipLaunchKernelGGL((dkvmn_kernel<1>), dim3(BB), dim3(512), 0, stream,
                           q_data, qa_data, target, q_embed, qa_embed, init_mv,
                           erase_b, add_b, input_b, read_b, predict_w, predict_b, ws, out);
    } else {
        hipLaunchKernelGGL((dkvmn_kernel<0>), dim3(BB), dim3(512), 0, stream,
                           q_data, qa_data, target, q_embed, qa_embed, init_mv,
                           erase_b, add_b, input_b, read_b, predict_w, predict_b, ws, out);
    }
    hipLaunchKernelGGL(finish_kernel, dim3(1), dim3(1), 0, stream, ws, out);
}

// Round 4
// 1026.334 us; speedup vs baseline: 4.4039x; 1.3952x over previous
//
#include <hip/hip_runtime.h>
#include <hip/hip_bf16.h>
#include <math.h>

#define BB 512
#define SS 512
#define MM 64
#define DK 128
#define DV 256
#define DF 128
#define CHUNK 16
#define NCHUNK (SS/CHUNK)

typedef __attribute__((ext_vector_type(8))) short s8v;   // 8 bf16 = 4 VGPRs
typedef __attribute__((ext_vector_type(4))) float f4v;   // MFMA accumulator

#define MFMA16(a,b,c) __builtin_amdgcn_mfma_f32_16x16x32_bf16((a),(b),(c),0,0,0)

// ---- workspace layout ----
// floats [0..15]: loss accumulators.  u16 region at ws+16 floats:
//   EAP  : erase|add packed B-frags, N=512 (0-255 erase, 256-511 add), K=256
//   KTP  : key    packed, N=64,  K=128
//   ITP  : input  packed, N=128, K=128
//   RTP  : read   packed, N=128, K=384
//   QTAB : q_embed  as bf16 [10001][128]
//   QATAB: qa_embed as bf16 [20001][256]
#define EAP_OFF 0
#define KTP_OFF 131072
#define ITP_OFF 139264
#define RTP_OFF 155648
#define QTAB_OFF 204800
#define QATAB_OFF (QTAB_OFF + 10001*DK)          // 1484928
#define WS_U16_TOTAL (QATAB_OFF + 20001*DV)      // 6605184
#define WS_NEED_BYTES (64 + 2*(size_t)WS_U16_TOTAL)

__device__ __forceinline__ unsigned short f2bf(float x) {
    union { float f; unsigned u; } v; v.f = x;
    unsigned r = v.u + 0x7fffu + ((v.u >> 16) & 1u);
    return (unsigned short)(r >> 16);
}
__device__ __forceinline__ float bf2f(unsigned short h) {
    union { unsigned u; float f; } v; v.u = ((unsigned)h) << 16;
    return v.f;
}
__device__ __forceinline__ float sigmoidf_(float x) { return 1.0f / (1.0f + __expf(-x)); }
__device__ __forceinline__ float fast_tanh(float x) {
    float e = __expf(2.0f * x);
    return 1.0f - 2.0f / (e + 1.0f);
}

__global__ void prep_kernel(const float* __restrict__ ew, const float* __restrict__ aw,
                            const float* __restrict__ km, const float* __restrict__ iw,
                            const float* __restrict__ rw,
                            const float* __restrict__ qe, const float* __restrict__ qae,
                            int do_tab, float* __restrict__ wsf) {
    int tid = blockIdx.x * 256 + threadIdx.x;
    int stride = gridDim.x * 256;
    if (tid < 2) wsf[tid] = 0.0f;
    unsigned short* bp = (unsigned short*)(wsf + 16);

    for (int i = tid; i < 131072; i += stride) {           // EAP: nf<32, ks<8
        int e = i & 7, l = (i >> 3) & 63, ks = (i >> 9) & 7, nf = i >> 12;
        int k = ks*32 + (l >> 4)*8 + e;
        int n = nf*16 + (l & 15);
        float v = (n < 256) ? ew[n*DV + k] : aw[(n-256)*DV + k];
        bp[EAP_OFF + i] = f2bf(v);
    }
    for (int i = tid; i < 8192; i += stride) {             // KTP: nf<4, ks<4
        int e = i & 7, l = (i >> 3) & 63, ks = (i >> 9) & 3, nf = i >> 11;
        int k = ks*32 + (l >> 4)*8 + e;
        int m = nf*16 + (l & 15);
        bp[KTP_OFF + i] = f2bf(km[m*DK + k]);
    }
    for (int i = tid; i < 16384; i += stride) {            // ITP: nf<8, ks<4
        int e = i & 7, l = (i >> 3) & 63, ks = (i >> 9) & 3, nf = i >> 11;
        int k = ks*32 + (l >> 4)*8 + e;
        int f = nf*16 + (l & 15);
        bp[ITP_OFF + i] = f2bf(iw[f*DK + k]);
    }
    for (int i = tid; i < 49152; i += stride) {            // RTP: nf<8, ks<12
        int e = i & 7, l = (i >> 3) & 63, g = i >> 9;
        int ks = g % 12, nf = g / 12;
        int j = ks*32 + (l >> 4)*8 + e;
        int f = nf*16 + (l & 15);
        bp[RTP_OFF + i] = f2bf(rw[f*(DV+DF) + j]);
    }
    if (do_tab) {
        for (int i = tid; i < 10001*DK; i += stride) bp[QTAB_OFF + i]  = f2bf(qe[i]);
        for (int i = tid; i < 20001*DV; i += stride) bp[QATAB_OFF + i] = f2bf(qae[i]);
    }
}

// LDS (byte offsets into smem[54272]):
//  qa16  [16][512B] bf16 swizzled   @ 0
//  q16   [16][256B] bf16 swizzled   @ 8192
//  cat16 [16][768B] bf16 swizzled   @ 12288   cols 0-255 read, 256-383 ie
//  sc_f  [16][68] f32               @ 24576   scores -> softmax w
//  er16  [16][264] bf16             @ 28928   (aliased by rce_f [16][132] f32)
//  ad16  [16][264] bf16             @ 37376
//  rdp   [16][264] bf16             @ 45824   half1 read-partials
template<int TAB16>
__launch_bounds__(512, 2)   // 128-VGPR cap: 2 blocks/CU is all grid=512 allows; (512,4) forced 64 VGPRs -> 2GB scratch spills
__global__ void dkvmn_kernel(const int* __restrict__ q_data, const int* __restrict__ qa_data,
                             const float* __restrict__ target,
                             const float* __restrict__ q_embed, const float* __restrict__ qa_embed,
                             const float* __restrict__ init_mv,
                             const float* __restrict__ erase_b, const float* __restrict__ add_b,
                             const float* __restrict__ input_b, const float* __restrict__ read_b,
                             const float* __restrict__ predict_w, const float* __restrict__ predict_b,
                             float* __restrict__ ws, float* __restrict__ out) {
    __shared__ __align__(128) char smem[54272];
    char*           qa16 = smem;
    char*           q16  = smem + 8192;
    char*           cat16= smem + 12288;
    float*          sc_f = (float*)(smem + 24576);
    unsigned short* er16 = (unsigned short*)(smem + 28928);
    unsigned short* ad16 = (unsigned short*)(smem + 37376);
    unsigned short* rdp  = (unsigned short*)(smem + 45824);
    float*          rce_f= (float*)(smem + 28928);   // alias er16 (dead after B4)

    const int b    = blockIdx.x;
    const int tid  = threadIdx.x;
    const int lane = tid & 63;
    const int wave = tid >> 6;       // 0..7
    const int arow = lane & 15;
    const int ag   = lane >> 4;
    const int d    = tid & 255;
    const int half = tid >> 8;

    const unsigned short* wsb = (const unsigned short*)(ws + 16);
    const s8v* eap = (const s8v*)(wsb + EAP_OFF);
    const s8v* ktp = (const s8v*)(wsb + KTP_OFF);
    const s8v* itp = (const s8v*)(wsb + ITP_OFF);
    const s8v* rtp = (const s8v*)(wsb + RTP_OFF);
    const unsigned short* qtab  = wsb + QTAB_OFF;
    const unsigned short* qatab = wsb + QATAB_OFF;

    // Mv state: thread (d, half) owns mv[m], m = half*32 + i
    float mv[32];
    #pragma unroll
    for (int i = 0; i < 32; ++i) mv[i] = init_mv[(half*32 + i)*DV + d];

    float biasEA[4];
    #pragma unroll
    for (int i = 0; i < 4; ++i) {
        int n = (wave*4 + i)*16 + arow;
        biasEA[i] = (n < 256) ? erase_b[n] : add_b[n - 256];
    }
    float ib0 = 0.f, ib1 = 0.f;
    if (wave >= 4) {
        ib0 = input_b[((wave-4)*2 + 0)*16 + arow];
        ib1 = input_b[((wave-4)*2 + 1)*16 + arow];
    }
    const float rb    = read_b[wave*16 + arow];
    const float pw_lo = predict_w[lane];
    const float pw_hi = predict_w[lane + 64];

    // ---- gather pipeline state ----
    const int base = b * SS;
    const int qc  = tid & 31;   // q col-unit (4 bf16)
    const int qr  = tid >> 5;   // q row
    const int ac  = tid & 63;   // qa col-unit
    const int ar0 = tid >> 6;   // qa rows ar0, ar0+8
    int iq, ia0, ia1, jq, ja0, ja1;
    ushort4 pq, pa0, pa1;
    float4  fq, fa0, fa1;

    auto loadidx = [&](int cc, int& x, int& y0, int& y1) {
        x  = q_data [base + cc*CHUNK + qr];
        y0 = qa_data[base + cc*CHUNK + ar0];
        y1 = qa_data[base + cc*CHUNK + ar0 + 8];
    };
    auto loadrows = [&]() {
        if constexpr (TAB16) {
            pq  = *(const ushort4*)(qtab  + iq *DK + qc*4);
            pa0 = *(const ushort4*)(qatab + ia0*DV + ac*4);
            pa1 = *(const ushort4*)(qatab + ia1*DV + ac*4);
        } else {
            fq  = *(const float4*)(q_embed  + iq *DK + qc*4);
            fa0 = *(const float4*)(qa_embed + ia0*DV + ac*4);
            fa1 = *(const float4*)(qa_embed + ia1*DV + ac*4);
        }
    };
    auto storerows = [&]() {
        ushort4 vq, v0, v1;
        if constexpr (TAB16) { vq = pq; v0 = pa0; v1 = pa1; }
        else {
            vq.x = f2bf(fq.x);  vq.y = f2bf(fq.y);  vq.z = f2bf(fq.z);  vq.w = f2bf(fq.w);
            v0.x = f2bf(fa0.x); v0.y = f2bf(fa0.y); v0.z = f2bf(fa0.z); v0.w = f2bf(fa0.w);
            v1.x = f2bf(fa1.x); v1.y = f2bf(fa1.y); v1.z = f2bf(fa1.z); v1.w = f2bf(fa1.w);
        }
        *(ushort4*)(q16  + ((qr*256 + qc*8)      ^ ((qr  & 7) << 4))) = vq;
        *(ushort4*)(qa16 + ((ar0*512 + ac*8)     ^ ((ar0 & 7) << 4))) = v0;
        *(ushort4*)(qa16 + (((ar0+8)*512 + ac*8) ^ (((ar0+8) & 7) << 4))) = v1;
    };

    loadidx(0, iq, ia0, ia1);
    loadrows();
    loadidx(1, jq, ja0, ja1);

    float local_loss = 0.0f, local_cnt = 0.0f;

    for (int c = 0; c < NCHUNK; ++c) {
        storerows();
        __syncthreads();                               // B1: gathers in LDS
        iq = jq; ia0 = ja0; ia1 = ja1;
        if (c + 1 < NCHUNK) loadrows();                // prefetch next chunk rows
        { int c2 = (c + 2 < NCHUNK) ? c + 2 : NCHUNK - 1; loadidx(c2, jq, ja0, ja1); }

        // ---- scores (waves 0-3) | ie (waves 4-7) ----
        if (wave < 4) {
            f4v cc = {0.f,0.f,0.f,0.f};
            #pragma unroll
            for (int ks = 0; ks < 4; ++ks) {
                s8v a = *(const s8v*)(q16 + ((arow*256 + ks*64 + ag*16) ^ ((arow & 7) << 4)));
                cc = MFMA16(a, ktp[(wave*4 + ks)*64 + lane], cc);
            }
            int m = wave*16 + arow;
            #pragma unroll
            for (int r = 0; r < 4; ++r) sc_f[(ag*4 + r)*68 + m] = cc[r];
        } else {
            s8v aq[4];
            #pragma unroll
            for (int ks = 0; ks < 4; ++ks)
                aq[ks] = *(const s8v*)(q16 + ((arow*256 + ks*64 + ag*16) ^ ((arow & 7) << 4)));
            #pragma unroll
            for (int i = 0; i < 2; ++i) {
                int nf = (wave - 4)*2 + i;
                f4v cc = {0.f,0.f,0.f,0.f};
                #pragma unroll
                for (int ks = 0; ks < 4; ++ks)
                    cc = MFMA16(aq[ks], itp[(nf*4 + ks)*64 + lane], cc);
                int f = nf*16 + arow;
                float bias = i ? ib1 : ib0;
                #pragma unroll
                for (int r = 0; r < 4; ++r) {
                    int row = ag*4 + r;
                    *(unsigned short*)(cat16 + ((row*768 + (256 + f)*2) ^ ((row & 7) << 4))) =
                        f2bf(fast_tanh(cc[r] + bias));
                }
            }
        }

        // ---- erase|add MFMA (all waves): wave owns 4 nf tiles ----
        {
            s8v af[8];
            #pragma unroll
            for (int ks = 0; ks < 8; ++ks)
                af[ks] = *(const s8v*)(qa16 + ((arow*512 + ks*64 + ag*16) ^ ((arow & 7) << 4)));
            #pragma unroll
            for (int i = 0; i < 4; ++i) {
                const s8v* bp2 = eap + ((wave*4 + i)*8)*64 + lane;
                f4v cc = {0.f,0.f,0.f,0.f};
                #pragma unroll
                for (int ks = 0; ks < 8; ++ks) cc = MFMA16(af[ks], bp2[ks*64], cc);
                int n = (wave*4 + i)*16 + arow;
                if (wave < 4) {
                    #pragma unroll
                    for (int r = 0; r < 4; ++r)
                        er16[(ag*4 + r)*264 + n] = f2bf(sigmoidf_(cc[r] + biasEA[i]));
                } else {
                    #pragma unroll
                    for (int r = 0; r < 4; ++r)
                        ad16[(ag*4 + r)*264 + (n - 256)] = f2bf(fast_tanh(cc[r] + biasEA[i]));
                }
            }
        }
        __syncthreads();                               // B2

        // ---- softmax: 2 rows per wave ----
        #pragma unroll
        for (int k = 0; k < 2; ++k) {
            int rr = wave*2 + k;
            float sc = sc_f[rr*68 + lane];
            float mx = sc;
            #pragma unroll
            for (int off = 32; off; off >>= 1) mx = fmaxf(mx, __shfl_xor(mx, off));
            float e = __expf(sc - mx);
            float sum = e;
            #pragma unroll
            for (int off = 32; off; off >>= 1) sum += __shfl_xor(sum, off);
            sc_f[rr*68 + lane] = e / sum;
        }
        __syncthreads();                               // B3

        // ---- recurrence: thread (d,half) owns 32 m-slots ----
        for (int s = 0; s < CHUNK; ++s) {
            float e = bf2f(er16[s*264 + d]);
            float a = bf2f(ad16[s*264 + d]);
            const float4* wr4 = (const float4*)(sc_f + s*68 + half*32);
            float r0 = 0.f, r1 = 0.f, r2 = 0.f, r3 = 0.f;
            #pragma unroll
            for (int j = 0; j < 8; ++j) {
                float4 w = wr4[j];
                r0 = fmaf(w.x, mv[j*4+0], r0); mv[j*4+0] = fmaf(w.x, fmaf(-mv[j*4+0], e, a), mv[j*4+0]);
                r1 = fmaf(w.y, mv[j*4+1], r1); mv[j*4+1] = fmaf(w.y, fmaf(-mv[j*4+1], e, a), mv[j*4+1]);
                r2 = fmaf(w.z, mv[j*4+2], r2); mv[j*4+2] = fmaf(w.z, fmaf(-mv[j*4+2], e, a), mv[j*4+2]);
                r3 = fmaf(w.w, mv[j*4+3], r3); mv[j*4+3] = fmaf(w.w, fmaf(-mv[j*4+3], e, a), mv[j*4+3]);
            }
            float rd = (r0 + r1) + (r2 + r3);
            if (half == 0) {
                *(unsigned short*)(cat16 + ((s*768 + d*2) ^ ((s & 7) << 4))) = f2bf(rd);
            } else {
                rdp[s*264 + d] = f2bf(rd);
            }
        }
        __syncthreads();                               // B4

        // ---- combine read halves (half0 waves) ----
        if (half == 0) {
            #pragma unroll
            for (int s = 0; s < CHUNK; ++s) {
                unsigned short* p = (unsigned short*)(cat16 + ((s*768 + d*2) ^ ((s & 7) << 4)));
                *p = f2bf(bf2f(*p) + bf2f(rdp[s*264 + d]));
            }
        }
        __syncthreads();                               // B5

        // ---- rce MFMA: wave owns nf = wave, K=384 ----
        {
            f4v cc = {0.f,0.f,0.f,0.f};
            #pragma unroll
            for (int ks = 0; ks < 12; ++ks) {
                s8v a = *(const s8v*)(cat16 + ((arow*768 + ks*64 + ag*16) ^ ((arow & 7) << 4)));
                cc = MFMA16(a, rtp[(wave*12 + ks)*64 + lane], cc);
            }
            int f = wave*16 + arow;
            #pragma unroll
            for (int r = 0; r < 4; ++r)
                rce_f[(ag*4 + r)*132 + f] = fast_tanh(cc[r] + rb);
        }
        __syncthreads();                               // B6

        // ---- pred + outputs + loss: 2 rows per wave ----
        #pragma unroll
        for (int k = 0; k < 2; ++k) {
            int r = wave*2 + k;
            float p = fmaf(pw_lo, rce_f[r*132 + lane], pw_hi * rce_f[r*132 + 64 + lane]);
            #pragma unroll
            for (int off = 32; off; off >>= 1) p += __shfl_xor(p, off);
            if (lane == 0) {
                p += predict_b[0];
                int gi = b*SS + c*CHUNK + r;
                float t = target[gi];
                bool mask = t >= 0.0f;
                out[gi] = sigmoidf_(p);
                float pm = mask ? p : 0.0f;
                out[BB*SS + 1 + gi] = sigmoidf_(pm);
                out[2*BB*SS + 1 + gi] = mask ? t : 0.0f;
                if (mask) {
                    local_loss += fmaxf(p, 0.0f) - p*t + log1pf(__expf(-fabsf(p)));
                    local_cnt  += 1.0f;
                }
            }
        }
        // no barrier: next storerows touches only q16/qa16 (readers done at B2)
    }

    #pragma unroll
    for (int off = 32; off; off >>= 1) {
        local_loss += __shfl_xor(local_loss, off);
        local_cnt  += __shfl_xor(local_cnt, off);
    }
    if (lane == 0) {
        atomicAdd(&ws[0], local_loss);
        atomicAdd(&ws[1], local_cnt);
    }
}

__global__ void finish_kernel(const float* __restrict__ ws, float* __restrict__ out) {
    out[BB*SS] = ws[0] / fmaxf(ws[1], 1.0f);
}

extern "C" void kernel_launch(void* const* d_in, const int* in_sizes, int n_in,
                              void* d_out, int out_size, void* d_ws, size_t ws_size,
                              hipStream_t stream) {
    const int*   q_data    = (const int*)d_in[0];
    const int*   qa_data   = (const int*)d_in[1];
    const float* target    = (const float*)d_in[2];
    const float* q_embed   = (const float*)d_in[3];
    const float* qa_embed  = (const float*)d_in[4];
    const float* key_mem   = (const float*)d_in[5];
    const float* init_mv   = (const float*)d_in[6];
    const float* erase_w   = (const float*)d_in[7];
    const float* erase_b   = (const float*)d_in[8];
    const float* add_w     = (const float*)d_in[9];
    const float* add_b     = (const float*)d_in[10];
    const float* input_w   = (const float*)d_in[11];
    const float* input_b   = (const float*)d_in[12];
    const float* read_w    = (const float*)d_in[13];
    const float* read_b    = (const float*)d_in[14];
    const float* predict_w = (const float*)d_in[15];
    const float* predict_b = (const float*)d_in[16];

    float* ws  = (float*)d_ws;
    float* out = (float*)d_out;

    int tab = (ws_size >= WS_NEED_BYTES) ? 1 : 0;

    hipLaunchKernelGGL(prep_kernel, dim3(1024), dim3(256), 0, stream,
                       erase_w, add_w, key_mem, input_w, read_w, q_embed, qa_embed, tab, ws);
    if (tab) {
        hipLaunchKernelGGL((dkvmn_kernel<1>), dim3(BB), dim3(512), 0, stream,
                           q_data, qa_data, target, q_embed, qa_embed, init_mv,
                           erase_b, add_b, input_b, read_b, predict_w, predict_b, ws, out);
    } else {
        hipLaunchKernelGGL((dkvmn_kernel<0>), dim3(BB), dim3(512), 0, stream,
                           q_data, qa_data, target, q_embed, qa_embed, init_mv,
                           erase_b, add_b, input_b, read_b, predict_w, predict_b, ws, out);
    }
    hipLaunchKernelGGL(finish_kernel, dim3(1), dim3(1), 0, stream, ws, out);
}

// Round 5
// 754.375 us; speedup vs baseline: 5.9916x; 1.3605x over previous
//
#include <hip/hip_runtime.h>
#include <hip/hip_bf16.h>
#include <math.h>

#define BB 512
#define SS 512
#define MM 64
#define DK 128
#define DV 256
#define DF 128
#define CHUNK 16
#define NCHUNK (SS/CHUNK)

typedef __attribute__((ext_vector_type(8))) short s8v;            // 8 bf16
typedef __attribute__((ext_vector_type(4))) float f4v;            // MFMA acc
typedef __attribute__((ext_vector_type(8))) unsigned short u16x8; // 16B of bf16

#define MFMA16(a,b,c) __builtin_amdgcn_mfma_f32_16x16x32_bf16((a),(b),(c),0,0,0)

// ---- workspace layout ----
// ws[0..15] floats: loss accumulators. u16 pack region at byte 64:
#define EAP_OFF 0         // erase|add packed B-frags, N=512, K=256 (131072 u16)
#define KTP_OFF 131072    // key   packed, N=64,  K=128 (8192)
#define ITP_OFF 139264    // input packed, N=128, K=128 (16384)
#define RTP_OFF 155648    // read  packed, N=128, K=384 (49152) -> end 204800
// byte offsets from ws base:
#define WTAB_BYTE 409664                      // f32 [10001][64]   softmax'd w
#define IET_BYTE  2969920                     // bf16 [10001][128] tanh'd ie
#define EAT_BYTE  5530176                     // bf16 [20001][512] sig(er)|tanh(ad)
#define WS_NEED2  26011200ull

__device__ __forceinline__ unsigned short f2bf(float x) {
    union { float f; unsigned u; } v; v.f = x;
    unsigned r = v.u + 0x7fffu + ((v.u >> 16) & 1u);
    return (unsigned short)(r >> 16);
}
__device__ __forceinline__ float bf2f(unsigned short h) {
    union { unsigned u; float f; } v; v.u = ((unsigned)h) << 16;
    return v.f;
}
__device__ __forceinline__ float sigmoidf_(float x) { return 1.0f / (1.0f + __expf(-x)); }
__device__ __forceinline__ float fast_tanh(float x) {
    float e = __expf(2.0f * x);
    return 1.0f - 2.0f / (e + 1.0f);
}

// ======================= prep: pack weights =======================
__global__ void prep_kernel(const float* __restrict__ ew, const float* __restrict__ aw,
                            const float* __restrict__ km, const float* __restrict__ iw,
                            const float* __restrict__ rw, float* __restrict__ wsf) {
    int tid = blockIdx.x * 256 + threadIdx.x;
    int stride = gridDim.x * 256;
    if (tid < 2) wsf[tid] = 0.0f;
    unsigned short* bp = (unsigned short*)(wsf + 16);

    for (int i = tid; i < 131072; i += stride) {           // EAP: nf<32, ks<8
        int e = i & 7, l = (i >> 3) & 63, ks = (i >> 9) & 7, nf = i >> 12;
        int k = ks*32 + (l >> 4)*8 + e;
        int n = nf*16 + (l & 15);
        float v = (n < 256) ? ew[n*DV + k] : aw[(n-256)*DV + k];
        bp[EAP_OFF + i] = f2bf(v);
    }
    for (int i = tid; i < 8192; i += stride) {             // KTP: nf<4, ks<4
        int e = i & 7, l = (i >> 3) & 63, ks = (i >> 9) & 3, nf = i >> 11;
        int k = ks*32 + (l >> 4)*8 + e;
        int m = nf*16 + (l & 15);
        bp[KTP_OFF + i] = f2bf(km[m*DK + k]);
    }
    for (int i = tid; i < 16384; i += stride) {            // ITP: nf<8, ks<4
        int e = i & 7, l = (i >> 3) & 63, ks = (i >> 9) & 3, nf = i >> 11;
        int k = ks*32 + (l >> 4)*8 + e;
        int f = nf*16 + (l & 15);
        bp[ITP_OFF + i] = f2bf(iw[f*DK + k]);
    }
    for (int i = tid; i < 49152; i += stride) {            // RTP: nf<8, ks<12
        int e = i & 7, l = (i >> 3) & 63, g = i >> 9;
        int ks = g % 12, nf = g / 12;
        int j = ks*32 + (l >> 4)*8 + e;
        int f = nf*16 + (l & 15);
        bp[RTP_OFF + i] = f2bf(rw[f*(DV+DF) + j]);
    }
}

// ======================= table kernel: per-unique-ID precompute =======================
// blocks [0,157): q-tables (w_table, ie_table); blocks [157,470): qa-tables (ea_table)
__launch_bounds__(256, 1)
__global__ void table_kernel(const float* __restrict__ q_embed, const float* __restrict__ qa_embed,
                             const float* __restrict__ erase_b, const float* __restrict__ add_b,
                             const float* __restrict__ input_b,
                             float* __restrict__ ws) {
    __shared__ __align__(128) char tsm[98304];
    const int tid  = threadIdx.x;
    const int lane = tid & 63;
    const int wave = tid >> 6;       // 0..3
    const int arow = lane & 15;
    const int ag   = lane >> 4;

    const unsigned short* wsb = (const unsigned short*)(ws + 16);
    const s8v* eap = (const s8v*)(wsb + EAP_OFF);
    const s8v* ktp = (const s8v*)(wsb + KTP_OFF);
    const s8v* itp = (const s8v*)(wsb + ITP_OFF);
    float*          wtab = (float*)((char*)ws + WTAB_BYTE);
    unsigned short* iet  = (unsigned short*)((char*)ws + IET_BYTE);
    unsigned short* eat  = (unsigned short*)((char*)ws + EAT_BYTE);

    if (blockIdx.x < 157) {
        // ---------------- q block: 64 rows of q_embed ----------------
        const int r0 = blockIdx.x * 64;
        char*  q16   = tsm;                    // [64][256B] bf16 swizzled
        float* sc    = (float*)(tsm + 16384);  // [64][68] f32
        unsigned short* iest = (unsigned short*)(tsm + 33792); // [64][128]

        #pragma unroll
        for (int it = 0; it < 8; ++it) {                     // stage 64x128 f32 -> bf16
            int u = it*256 + tid;
            int row = u >> 5, c4 = u & 31;
            int sr = r0 + row; if (sr > 10000) sr = 10000;
            float4 v = *(const float4*)(q_embed + sr*DK + c4*4);
            ushort4 p; p.x = f2bf(v.x); p.y = f2bf(v.y); p.z = f2bf(v.z); p.w = f2bf(v.w);
            *(ushort4*)(q16 + ((row*256 + c4*8) ^ ((row & 7) << 4))) = p;
        }
        __syncthreads();

        // scores MFMA: m-tile = wave
        {
            s8v a[4];
            #pragma unroll
            for (int ks = 0; ks < 4; ++ks)
                a[ks] = *(const s8v*)(q16 + (((wave*16+arow)*256 + ks*64 + ag*16) ^ ((arow & 7) << 4)));
            #pragma unroll
            for (int j = 0; j < 4; ++j) {
                f4v cc = {0.f,0.f,0.f,0.f};
                #pragma unroll
                for (int ks = 0; ks < 4; ++ks) cc = MFMA16(a[ks], ktp[(j*4 + ks)*64 + lane], cc);
                #pragma unroll
                for (int r = 0; r < 4; ++r)
                    sc[(wave*16 + ag*4 + r)*68 + j*16 + arow] = cc[r];
            }
            __syncthreads();

            // softmax rows -> wtab
            #pragma unroll
            for (int k = 0; k < 16; ++k) {
                int rr = wave*16 + k;
                float v = sc[rr*68 + lane];
                float mx = v;
                #pragma unroll
                for (int off = 32; off; off >>= 1) mx = fmaxf(mx, __shfl_xor(mx, off));
                float e = __expf(v - mx);
                float sum = e;
                #pragma unroll
                for (int off = 32; off; off >>= 1) sum += __shfl_xor(sum, off);
                if (r0 + rr < 10001) wtab[(r0 + rr)*64 + lane] = e / sum;
            }

            // ie MFMA: 8 n-tiles
            #pragma unroll
            for (int j = 0; j < 8; ++j) {
                f4v cc = {0.f,0.f,0.f,0.f};
                #pragma unroll
                for (int ks = 0; ks < 4; ++ks) cc = MFMA16(a[ks], itp[(j*4 + ks)*64 + lane], cc);
                float bias = input_b[j*16 + arow];
                #pragma unroll
                for (int r = 0; r < 4; ++r)
                    iest[(wave*16 + ag*4 + r)*128 + j*16 + arow] = f2bf(fast_tanh(cc[r] + bias));
            }
        }
        __syncthreads();
        #pragma unroll
        for (int it = 0; it < 4; ++it) {                     // coalesced store ie
            int u = it*256 + tid;
            int row = u >> 4, c8 = u & 15;
            if (r0 + row < 10001)
                *(u16x8*)(iet + (r0 + row)*128 + c8*8) = *(const u16x8*)(iest + row*128 + c8*8);
        }
    } else {
        // ---------------- qa block: 64 rows of qa_embed ----------------
        const int r0 = (blockIdx.x - 157) * 64;
        char* qa16 = tsm;                                    // [64][512B] swizzled
        unsigned short* east = (unsigned short*)(tsm + 32768); // [64][512]

        #pragma unroll
        for (int it = 0; it < 16; ++it) {                    // stage 64x256 f32 -> bf16
            int u = it*256 + tid;
            int row = u >> 6, c4 = u & 63;
            int sr = r0 + row; if (sr > 20000) sr = 20000;
            float4 v = *(const float4*)(qa_embed + sr*DV + c4*4);
            ushort4 p; p.x = f2bf(v.x); p.y = f2bf(v.y); p.z = f2bf(v.z); p.w = f2bf(v.w);
            *(ushort4*)(qa16 + ((row*512 + c4*8) ^ ((row & 7) << 4))) = p;
        }
        __syncthreads();

        {
            s8v af[8];
            #pragma unroll
            for (int ks = 0; ks < 8; ++ks)
                af[ks] = *(const s8v*)(qa16 + (((wave*16+arow)*512 + ks*64 + ag*16) ^ ((arow & 7) << 4)));
            #pragma unroll
            for (int i = 0; i < 32; ++i) {
                f4v cc = {0.f,0.f,0.f,0.f};
                #pragma unroll
                for (int ks = 0; ks < 8; ++ks) cc = MFMA16(af[ks], eap[(i*8 + ks)*64 + lane], cc);
                int n = i*16 + arow;
                float bias = (n < 256) ? erase_b[n] : add_b[n - 256];
                #pragma unroll
                for (int r = 0; r < 4; ++r) {
                    float v = cc[r] + bias;
                    float res = (n < 256) ? sigmoidf_(v) : fast_tanh(v);
                    east[(wave*16 + ag*4 + r)*512 + n] = f2bf(res);
                }
            }
        }
        __syncthreads();
        #pragma unroll
        for (int it = 0; it < 16; ++it) {                    // coalesced store er|ad
            int u = it*256 + tid;
            int row = u >> 6, c8 = u & 63;
            if (r0 + row < 20001)
                *(u16x8*)(eat + (size_t)(r0 + row)*512 + c8*8) = *(const u16x8*)(east + row*512 + c8*8);
        }
    }
}

// ======================= scan kernel: recurrence + rce + pred =======================
// LDS: cat16 [16][768B] swz @0 (12288) | wf [16][68]f32 @12288 (4352) |
//      ea [16][520]u16 @16640 (16640) | rdp [16][264]u16 @33280 (8448) |
//      rce_f [16][132]f32 @41728 (8448)  -> 50176 B
__launch_bounds__(512, 2)
__global__ void scan_kernel(const int* __restrict__ q_data, const int* __restrict__ qa_data,
                            const float* __restrict__ target,
                            const float* __restrict__ init_mv,
                            const float* __restrict__ read_b,
                            const float* __restrict__ predict_w, const float* __restrict__ predict_b,
                            float* __restrict__ ws, float* __restrict__ out) {
    __shared__ __align__(128) char smem[50176];
    char*           cat16 = smem;
    float*          wf    = (float*)(smem + 12288);
    unsigned short* eaL   = (unsigned short*)(smem + 16640);
    unsigned short* rdp   = (unsigned short*)(smem + 33280);
    float*          rce_f = (float*)(smem + 41728);

    const int b    = blockIdx.x;
    const int tid  = threadIdx.x;
    const int lane = tid & 63;
    const int wave = tid >> 6;       // 0..7
    const int arow = lane & 15;
    const int ag   = lane >> 4;
    const int d    = tid & 255;
    const int half = tid >> 8;

    const unsigned short* wsb = (const unsigned short*)(ws + 16);
    const s8v* rtp = (const s8v*)(wsb + RTP_OFF);
    const float*          wtab = (const float*)((const char*)ws + WTAB_BYTE);
    const unsigned short* iet  = (const unsigned short*)((const char*)ws + IET_BYTE);
    const unsigned short* eat  = (const unsigned short*)((const char*)ws + EAT_BYTE);

    float mv[32];
    #pragma unroll
    for (int i = 0; i < 32; ++i) mv[i] = init_mv[(half*32 + i)*DV + d];

    const float rb    = read_b[wave*16 + arow];
    const float pw_lo = predict_w[lane];
    const float pw_hi = predict_w[lane + 64];

    // gather roles
    const int base  = b * SS;
    const int erow  = tid >> 5;        // 0..15, ea row
    const int eunit = tid & 31;        // 32B unit of 1024B row
    const int role  = tid >> 8;        // wave-uniform: 0=wf, 1=ie
    const int grow  = (tid >> 4) & 15; // wf/ie row
    const int gunit = tid & 15;        // 16B unit of 256B row

    int iqa0, iq0, iqa1, iq1;
    u16x8 pe0, pe1, pie;
    float4 pwf;

    auto loadidx = [&](int cc, int& xa, int& xq) {
        xa = qa_data[base + cc*CHUNK + erow];
        xq = q_data [base + cc*CHUNK + grow];
    };
    auto loadrows = [&]() {
        const unsigned short* er_ptr = eat + (size_t)iqa0*512 + eunit*16;
        pe0 = *(const u16x8*)(er_ptr);
        pe1 = *(const u16x8*)(er_ptr + 8);
        if (role == 0) pwf = *(const float4*)(wtab + iq0*64 + gunit*4);
        else           pie = *(const u16x8*)(iet + (size_t)iq0*128 + gunit*8);
    };
    auto storerows = [&]() {
        *(u16x8*)(eaL + erow*520 + eunit*16)     = pe0;
        *(u16x8*)(eaL + erow*520 + eunit*16 + 8) = pe1;
        if (role == 0) *(float4*)((char*)wf + grow*272 + gunit*16) = pwf;
        else *(u16x8*)(cat16 + ((grow*768 + 512 + gunit*16) ^ ((grow & 7) << 4))) = pie;
    };

    loadidx(0, iqa0, iq0);
    loadrows();
    loadidx(1, iqa1, iq1);

    float local_loss = 0.0f, local_cnt = 0.0f;

    for (int c = 0; c < NCHUNK; ++c) {
        storerows();
        __syncthreads();                               // B1: tables staged
        iqa0 = iqa1; iq0 = iq1;
        if (c + 1 < NCHUNK) loadrows();
        { int c2 = (c + 2 < NCHUNK) ? c + 2 : NCHUNK - 1; loadidx(c2, iqa1, iq1); }

        // ---- recurrence: thread (d,half) owns 32 m-slots ----
        for (int s = 0; s < CHUNK; ++s) {
            float e = bf2f(eaL[s*520 + d]);
            float a = bf2f(eaL[s*520 + 256 + d]);
            const float4* wr4 = (const float4*)(wf + s*68 + half*32);
            float r0 = 0.f, r1 = 0.f, r2 = 0.f, r3 = 0.f;
            #pragma unroll
            for (int j = 0; j < 8; ++j) {
                float4 w = wr4[j];
                r0 = fmaf(w.x, mv[j*4+0], r0); mv[j*4+0] = fmaf(w.x, fmaf(-mv[j*4+0], e, a), mv[j*4+0]);
                r1 = fmaf(w.y, mv[j*4+1], r1); mv[j*4+1] = fmaf(w.y, fmaf(-mv[j*4+1], e, a), mv[j*4+1]);
                r2 = fmaf(w.z, mv[j*4+2], r2); mv[j*4+2] = fmaf(w.z, fmaf(-mv[j*4+2], e, a), mv[j*4+2]);
                r3 = fmaf(w.w, mv[j*4+3], r3); mv[j*4+3] = fmaf(w.w, fmaf(-mv[j*4+3], e, a), mv[j*4+3]);
            }
            float rd = (r0 + r1) + (r2 + r3);
            if (half == 0) {
                *(unsigned short*)(cat16 + ((s*768 + d*2) ^ ((s & 7) << 4))) = f2bf(rd);
            } else {
                rdp[s*264 + d] = f2bf(rd);
            }
        }
        __syncthreads();                               // B2

        if (half == 0) {                               // combine read halves
            #pragma unroll
            for (int s = 0; s < CHUNK; ++s) {
                unsigned short* p = (unsigned short*)(cat16 + ((s*768 + d*2) ^ ((s & 7) << 4)));
                *p = f2bf(bf2f(*p) + bf2f(rdp[s*264 + d]));
            }
        }
        __syncthreads();                               // B3

        // ---- rce MFMA: wave owns n-tile = wave, K=384 ----
        {
            f4v cc = {0.f,0.f,0.f,0.f};
            #pragma unroll
            for (int ks = 0; ks < 12; ++ks) {
                s8v a = *(const s8v*)(cat16 + ((arow*768 + ks*64 + ag*16) ^ ((arow & 7) << 4)));
                cc = MFMA16(a, rtp[(wave*12 + ks)*64 + lane], cc);
            }
            #pragma unroll
            for (int r = 0; r < 4; ++r)
                rce_f[(ag*4 + r)*132 + wave*16 + arow] = fast_tanh(cc[r] + rb);
        }
        __syncthreads();                               // B4

        // ---- pred + outputs + loss ----
        #pragma unroll
        for (int k = 0; k < 2; ++k) {
            int r = wave*2 + k;
            float p = fmaf(pw_lo, rce_f[r*132 + lane], pw_hi * rce_f[r*132 + 64 + lane]);
            #pragma unroll
            for (int off = 32; off; off >>= 1) p += __shfl_xor(p, off);
            if (lane == 0) {
                p += predict_b[0];
                int gi = b*SS + c*CHUNK + r;
                float t = target[gi];
                bool mask = t >= 0.0f;
                out[gi] = sigmoidf_(p);
                float pm = mask ? p : 0.0f;
                out[BB*SS + 1 + gi] = sigmoidf_(pm);
                out[2*BB*SS + 1 + gi] = mask ? t : 0.0f;
                if (mask) {
                    local_loss += fmaxf(p, 0.0f) - p*t + log1pf(__expf(-fabsf(p)));
                    local_cnt  += 1.0f;
                }
            }
        }
        // next storerows touches only ea/wf/cat16-ie: all readers done by B4
    }

    #pragma unroll
    for (int off = 32; off; off >>= 1) {
        local_loss += __shfl_xor(local_loss, off);
        local_cnt  += __shfl_xor(local_cnt, off);
    }
    if (lane == 0) {
        atomicAdd(&ws[0], local_loss);
        atomicAdd(&ws[1], local_cnt);
    }
}

// ======================= fallback: round-4 fused kernel (f32 embeds) =======================
__launch_bounds__(512, 2)
__global__ void fused_kernel(const int* __restrict__ q_data, const int* __restrict__ qa_data,
                             const float* __restrict__ target,
                             const float* __restrict__ q_embed, const float* __restrict__ qa_embed,
                             const float* __restrict__ init_mv,
                             const float* __restrict__ erase_b, const float* __restrict__ add_b,
                             const float* __restrict__ input_b, const float* __restrict__ read_b,
                             const float* __restrict__ predict_w, const float* __restrict__ predict_b,
                             float* __restrict__ ws, float* __restrict__ out) {
    __shared__ __align__(128) char smem[54272];
    char*           qa16 = smem;
    char*           q16  = smem + 8192;
    char*           cat16= smem + 12288;
    float*          sc_f = (float*)(smem + 24576);
    unsigned short* er16 = (unsigned short*)(smem + 28928);
    unsigned short* ad16 = (unsigned short*)(smem + 37376);
    unsigned short* rdp  = (unsigned short*)(smem + 45824);
    float*          rce_f= (float*)(smem + 28928);

    const int b    = blockIdx.x;
    const int tid  = threadIdx.x;
    const int lane = tid & 63;
    const int wave = tid >> 6;
    const int arow = lane & 15;
    const int ag   = lane >> 4;
    const int d    = tid & 255;
    const int half = tid >> 8;

    const unsigned short* wsb = (const unsigned short*)(ws + 16);
    const s8v* eap = (const s8v*)(wsb + EAP_OFF);
    const s8v* ktp = (const s8v*)(wsb + KTP_OFF);
    const s8v* itp = (const s8v*)(wsb + ITP_OFF);
    const s8v* rtp = (const s8v*)(wsb + RTP_OFF);

    float mv[32];
    #pragma unroll
    for (int i = 0; i < 32; ++i) mv[i] = init_mv[(half*32 + i)*DV + d];

    float biasEA[4];
    #pragma unroll
    for (int i = 0; i < 4; ++i) {
        int n = (wave*4 + i)*16 + arow;
        biasEA[i] = (n < 256) ? erase_b[n] : add_b[n - 256];
    }
    float ib0 = 0.f, ib1 = 0.f;
    if (wave >= 4) {
        ib0 = input_b[((wave-4)*2 + 0)*16 + arow];
        ib1 = input_b[((wave-4)*2 + 1)*16 + arow];
    }
    const float rb    = read_b[wave*16 + arow];
    const float pw_lo = predict_w[lane];
    const float pw_hi = predict_w[lane + 64];

    const int base = b * SS;
    const int qc  = tid & 31;
    const int qr  = tid >> 5;
    const int ac  = tid & 63;
    const int ar0 = tid >> 6;
    int iq, ia0, ia1, jq, ja0, ja1;
    float4 fq, fa0, fa1;

    auto loadidx = [&](int cc, int& x, int& y0, int& y1) {
        x  = q_data [base + cc*CHUNK + qr];
        y0 = qa_data[base + cc*CHUNK + ar0];
        y1 = qa_data[base + cc*CHUNK + ar0 + 8];
    };
    auto loadrows = [&]() {
        fq  = *(const float4*)(q_embed  + iq *DK + qc*4);
        fa0 = *(const float4*)(qa_embed + ia0*DV + ac*4);
        fa1 = *(const float4*)(qa_embed + ia1*DV + ac*4);
    };
    auto storerows = [&]() {
        ushort4 vq, v0, v1;
        vq.x = f2bf(fq.x);  vq.y = f2bf(fq.y);  vq.z = f2bf(fq.z);  vq.w = f2bf(fq.w);
        v0.x = f2bf(fa0.x); v0.y = f2bf(fa0.y); v0.z = f2bf(fa0.z); v0.w = f2bf(fa0.w);
        v1.x = f2bf(fa1.x); v1.y = f2bf(fa1.y); v1.z = f2bf(fa1.z); v1.w = f2bf(fa1.w);
        *(ushort4*)(q16  + ((qr*256 + qc*8)      ^ ((qr  & 7) << 4))) = vq;
        *(ushort4*)(qa16 + ((ar0*512 + ac*8)     ^ ((ar0 & 7) << 4))) = v0;
        *(ushort4*)(qa16 + (((ar0+8)*512 + ac*8) ^ (((ar0+8) & 7) << 4))) = v1;
    };

    loadidx(0, iq, ia0, ia1);
    loadrows();
    loadidx(1, jq, ja0, ja1);

    float local_loss = 0.0f, local_cnt = 0.0f;

    for (int c = 0; c < NCHUNK; ++c) {
        storerows();
        __syncthreads();
        iq = jq; ia0 = ja0; ia1 = ja1;
        if (c + 1 < NCHUNK) loadrows();
        { int c2 = (c + 2 < NCHUNK) ? c + 2 : NCHUNK - 1; loadidx(c2, jq, ja0, ja1); }

        if (wave < 4) {
            f4v cc = {0.f,0.f,0.f,0.f};
            #pragma unroll
            for (int ks = 0; ks < 4; ++ks) {
                s8v a = *(const s8v*)(q16 + ((arow*256 + ks*64 + ag*16) ^ ((arow & 7) << 4)));
                cc = MFMA16(a, ktp[(wave*4 + ks)*64 + lane], cc);
            }
            int m = wave*16 + arow;
            #pragma unroll
            for (int r = 0; r < 4; ++r) sc_f[(ag*4 + r)*68 + m] = cc[r];
        } else {
            s8v aq[4];
            #pragma unroll
            for (int ks = 0; ks < 4; ++ks)
                aq[ks] = *(const s8v*)(q16 + ((arow*256 + ks*64 + ag*16) ^ ((arow & 7) << 4)));
            #pragma unroll
            for (int i = 0; i < 2; ++i) {
                int nf = (wave - 4)*2 + i;
                f4v cc = {0.f,0.f,0.f,0.f};
                #pragma unroll
                for (int ks = 0; ks < 4; ++ks)
                    cc = MFMA16(aq[ks], itp[(nf*4 + ks)*64 + lane], cc);
                int f = nf*16 + arow;
                float bias = i ? ib1 : ib0;
                #pragma unroll
                for (int r = 0; r < 4; ++r) {
                    int row = ag*4 + r;
                    *(unsigned short*)(cat16 + ((row*768 + (256 + f)*2) ^ ((row & 7) << 4))) =
                        f2bf(fast_tanh(cc[r] + bias));
                }
            }
        }
        {
            s8v af[8];
            #pragma unroll
            for (int ks = 0; ks < 8; ++ks)
                af[ks] = *(const s8v*)(qa16 + ((arow*512 + ks*64 + ag*16) ^ ((arow & 7) << 4)));
            #pragma unroll
            for (int i = 0; i < 4; ++i) {
                const s8v* bp2 = eap + ((wave*4 + i)*8)*64 + lane;
                f4v cc = {0.f,0.f,0.f,0.f};
                #pragma unroll
                for (int ks = 0; ks < 8; ++ks) cc = MFMA16(af[ks], bp2[ks*64], cc);
                int n = (wave*4 + i)*16 + arow;
                if (wave < 4) {
                    #pragma unroll
                    for (int r = 0; r < 4; ++r)
                        er16[(ag*4 + r)*264 + n] = f2bf(sigmoidf_(cc[r] + biasEA[i]));
                } else {
                    #pragma unroll
                    for (int r = 0; r < 4; ++r)
                        ad16[(ag*4 + r)*264 + (n - 256)] = f2bf(fast_tanh(cc[r] + biasEA[i]));
                }
            }
        }
        __syncthreads();

        #pragma unroll
        for (int k = 0; k < 2; ++k) {
            int rr = wave*2 + k;
            float sc = sc_f[rr*68 + lane];
            float mx = sc;
            #pragma unroll
            for (int off = 32; off; off >>= 1) mx = fmaxf(mx, __shfl_xor(mx, off));
            float e = __expf(sc - mx);
            float sum = e;
            #pragma unroll
            for (int off = 32; off; off >>= 1) sum += __shfl_xor(sum, off);
            sc_f[rr*68 + lane] = e / sum;
        }
        __syncthreads();

        for (int s = 0; s < CHUNK; ++s) {
            float e = bf2f(er16[s*264 + d]);
            float a = bf2f(ad16[s*264 + d]);
            const float4* wr4 = (const float4*)(sc_f + s*68 + half*32);
            float r0 = 0.f, r1 = 0.f, r2 = 0.f, r3 = 0.f;
            #pragma unroll
            for (int j = 0; j < 8; ++j) {
                float4 w = wr4[j];
                r0 = fmaf(w.x, mv[j*4+0], r0); mv[j*4+0] = fmaf(w.x, fmaf(-mv[j*4+0], e, a), mv[j*4+0]);
                r1 = fmaf(w.y, mv[j*4+1], r1); mv[j*4+1] = fmaf(w.y, fmaf(-mv[j*4+1], e, a), mv[j*4+1]);
                r2 = fmaf(w.z, mv[j*4+2], r2); mv[j*4+2] = fmaf(w.z, fmaf(-mv[j*4+2], e, a), mv[j*4+2]);
                r3 = fmaf(w.w, mv[j*4+3], r3); mv[j*4+3] = fmaf(w.w, fmaf(-mv[j*4+3], e, a), mv[j*4+3]);
            }
            float rd = (r0 + r1) + (r2 + r3);
            if (half == 0) {
                *(unsigned short*)(cat16 + ((s*768 + d*2) ^ ((s & 7) << 4))) = f2bf(rd);
            } else {
                rdp[s*264 + d] = f2bf(rd);
            }
        }
        __syncthreads();

        if (half == 0) {
            #pragma unroll
            for (int s = 0; s < CHUNK; ++s) {
                unsigned short* p = (unsigned short*)(cat16 + ((s*768 + d*2) ^ ((s & 7) << 4)));
                *p = f2bf(bf2f(*p) + bf2f(rdp[s*264 + d]));
            }
        }
        __syncthreads();

        {
            f4v cc = {0.f,0.f,0.f,0.f};
            #pragma unroll
            for (int ks = 0; ks < 12; ++ks) {
                s8v a = *(const s8v*)(cat16 + ((arow*768 + ks*64 + ag*16) ^ ((arow & 7) << 4)));
                cc = MFMA16(a, rtp[(wave*12 + ks)*64 + lane], cc);
            }
            int f = wave*16 + arow;
            #pragma unroll
            for (int r = 0; r < 4; ++r)
                rce_f[(ag*4 + r)*132 + f] = fast_tanh(cc[r] + rb);
        }
        __syncthreads();

        #pragma unroll
        for (int k = 0; k < 2; ++k) {
            int r = wave*2 + k;
            float p = fmaf(pw_lo, rce_f[r*132 + lane], pw_hi * rce_f[r*132 + 64 + lane]);
            #pragma unroll
            for (int off = 32; off; off >>= 1) p += __shfl_xor(p, off);
            if (lane == 0) {
                p += predict_b[0];
                int gi = b*SS + c*CHUNK + r;
                float t = target[gi];
                bool mask = t >= 0.0f;
                out[gi] = sigmoidf_(p);
                float pm = mask ? p : 0.0f;
                out[BB*SS + 1 + gi] = sigmoidf_(pm);
                out[2*BB*SS + 1 + gi] = mask ? t : 0.0f;
                if (mask) {
                    local_loss += fmaxf(p, 0.0f) - p*t + log1pf(__expf(-fabsf(p)));
                    local_cnt  += 1.0f;
                }
            }
        }
    }

    #pragma unroll
    for (int off = 32; off; off >>= 1) {
        local_loss += __shfl_xor(local_loss, off);
        local_cnt  += __shfl_xor(local_cnt, off);
    }
    if (lane == 0) {
        atomicAdd(&ws[0], local_loss);
        atomicAdd(&ws[1], local_cnt);
    }
}

__global__ void finish_kernel(const float* __restrict__ ws, float* __restrict__ out) {
    out[BB*SS] = ws[0] / fmaxf(ws[1], 1.0f);
}

extern "C" void kernel_launch(void* const* d_in, const int* in_sizes, int n_in,
                              void* d_out, int out_size, void* d_ws, size_t ws_size,
                              hipStream_t stream) {
    const int*   q_data    = (const int*)d_in[0];
    const int*   qa_data   = (const int*)d_in[1];
    const float* target    = (const float*)d_in[2];
    const float* q_embed   = (const float*)d_in[3];
    const float* qa_embed  = (const float*)d_in[4];
    const float* key_mem   = (const float*)d_in[5];
    const float* init_mv   = (const float*)d_in[6];
    const float* erase_w   = (const float*)d_in[7];
    const float* erase_b   = (const float*)d_in[8];
    const float* add_w     = (const float*)d_in[9];
    const float* add_b     = (const float*)d_in[10];
    const float* input_w   = (const float*)d_in[11];
    const float* input_b   = (const float*)d_in[12];
    const float* read_w    = (const float*)d_in[13];
    const float* read_b    = (const float*)d_in[14];
    const float* predict_w = (const float*)d_in[15];
    const float* predict_b = (const float*)d_in[16];

    float* ws  = (float*)d_ws;
    float* out = (float*)d_out;

    hipLaunchKernelGGL(prep_kernel, dim3(256), dim3(256), 0, stream,
                       erase_w, add_w, key_mem, input_w, read_w, ws);
    if (ws_size >= WS_NEED2) {
        hipLaunchKernelGGL(table_kernel, dim3(470), dim3(256), 0, stream,
                           q_embed, qa_embed, erase_b, add_b, input_b, ws);
        hipLaunchKernelGGL(scan_kernel, dim3(BB), dim3(512), 0, stream,
                           q_data, qa_data, target, init_mv,
                           read_b, predict_w, predict_b, ws, out);
    } else {
        hipLaunchKernelGGL(fused_kernel, dim3(BB), dim3(512), 0, stream,
                           q_data, qa_data, target, q_embed, qa_embed, init_mv,
                           erase_b, add_b, input_b, read_b, predict_w, predict_b, ws, out);
    }
    hipLaunchKernelGGL(finish_kernel, dim3(1), dim3(1), 0, stream, ws, out);
}